// Round 1
// 500.904 us; speedup vs baseline: 1.1099x; 1.1099x over previous
//
#include <hip/hip_runtime.h>
#include <hip/hip_bf16.h>

#define B_ 8
#define T_ 2048
#define C_ 512
#define H_ 16
#define HS_ 32
#define BT_ (B_*T_)   // 16384 tokens
#define CL_ 64        // scan chunk length
#define NC_ (T_/CL_)  // 32 chunks
#define STF_ 1056     // floats per (bh,chunk) state: 1024 S + 32 P
#define WSZ_ 262144   // elements per 512x512 weight (2^18)

typedef __hip_bfloat16 bf16;
typedef __attribute__((ext_vector_type(8))) short short8;
typedef __attribute__((ext_vector_type(4))) float f32x4;

__device__ __forceinline__ float b2f(bf16 v) { return __bfloat162float(v); }
__device__ __forceinline__ bf16 f2b(float v) { return __float2bfloat16(v); }

// ---------------------------------------------------------------------------
// prep_combo: one launch does (a) xxx = x + (xshift-x)*maa_x, (b) hi/lo bf16
// split of the five 512x512 weights, (c) transpose+pad w1 -> [192][512] and
// wd1 -> [64][512], (d) transpose+pad w2 -> [512][192] bf16 for mix_mfma.
// Grid covers the concatenated index space exactly.
// ---------------------------------------------------------------------------
__global__ __launch_bounds__(256) void prep_combo_kernel(
    const float* __restrict__ x, const float* __restrict__ tmx,
    const float* __restrict__ Wr, const float* __restrict__ Wk,
    const float* __restrict__ Wv, const float* __restrict__ Wg,
    const float* __restrict__ Wo, const float* __restrict__ w1,
    const float* __restrict__ wd1, const float* __restrict__ w2,
    bf16* __restrict__ xxx, bf16* __restrict__ Wrb, bf16* __restrict__ Wkb,
    bf16* __restrict__ Wvb, bf16* __restrict__ Wgb, bf16* __restrict__ Wob,
    bf16* __restrict__ w1p, bf16* __restrict__ wd1p, bf16* __restrict__ w2p) {
  int idx = blockIdx.x * 256 + threadIdx.x;
  if (idx < BT_ * C_) {                       // token-shift mix input
    int c = idx & (C_ - 1);
    int t = (idx >> 9) & (T_ - 1);
    float xc = x[idx];
    float xp = (t == 0) ? 0.f : x[idx - C_];
    xxx[idx] = f2b(xc + (xp - xc) * tmx[c]);
    return;
  }
  idx -= BT_ * C_;
  if (idx < 5 * WSZ_) {                       // weight hi/lo split
    int w = idx >> 18;
    int i = idx & (WSZ_ - 1);
    const float* src = (w == 0) ? Wr : (w == 1) ? Wk : (w == 2) ? Wv
                     : (w == 3) ? Wg : Wo;
    bf16* dst = (w == 0) ? Wrb : (w == 1) ? Wkb : (w == 2) ? Wvb
              : (w == 3) ? Wgb : Wob;
    float s = src[i];
    bf16 hi = f2b(s);
    dst[i] = hi;
    dst[WSZ_ + i] = f2b(s - b2f(hi));
    return;
  }
  idx -= 5 * WSZ_;
  if (idx < 192 * 512) {                      // w1^T padded to 192 rows
    int n = idx >> 9, k = idx & (C_ - 1);
    w1p[idx] = f2b(n < 160 ? w1[k * 160 + n] : 0.f);
    return;
  }
  idx -= 192 * 512;
  if (idx < 64 * 512) {                       // wd1^T [64][512]
    int n = idx >> 9, k = idx & (C_ - 1);
    wd1p[idx] = f2b(wd1[k * 64 + n]);
    return;
  }
  idx -= 64 * 512;
  {                                           // w2^T padded [512][192]
    int c = idx / 192, n = idx - c * 192;     // n = f*32+d
    w2p[idx] = f2b(n < 160 ? w2[(size_t)n * C_ + c] : 0.f);
  }
}
#define PREP_N_ ((BT_*C_ + 5*WSZ_ + 192*512 + 64*512 + 512*192) / 256) // 38784

// ---------------------------------------------------------------------------
// MFMA GEMM: O = act(A @ Bw^T). BM=128, BK=32, 256 thr. (verified round 8)
// MODE: 0 bf16; 1 bf16+silu; 2 fp32; 3 bf16+tanh.  N = output stride.
// ---------------------------------------------------------------------------
template<int BN, int MODE, int SPLIT>
__global__ __launch_bounds__(256) void mfma_gemm_kernel(
    const bf16* __restrict__ A, const bf16* __restrict__ Bw,
    void* __restrict__ O, int N) {
  constexpr int BM = 128, BK = 32;
  constexpr int AE = BM * BK / 8;
  constexpr int BE = BN * BK / 8;
  __shared__ short8 Asm[AE];
  __shared__ short8 Bsm[BE];
  __shared__ short8 Lsm[SPLIT ? BE : 1];
  const int tid = threadIdx.x;
  const int lane = tid & 63;
  const int wave = tid >> 6;
  const int m0 = blockIdx.x * BM;
  const int n0 = blockIdx.y * BN;
  const int wm = (BN == 128) ? (wave >> 1) * 64 : wave * 32;
  const int wn = (BN == 128) ? (wave & 1) * 64 : 0;
  constexpr int MT = (BN == 128) ? 4 : 2;
  constexpr int NT = 4;
  f32x4 acc[MT][NT] = {};
  const int e0 = tid, e1 = tid + 256;
  const int r0 = ((e0 >> 6) << 4) | (e0 & 15), q0 = (e0 >> 4) & 3;
  const int r1 = ((e1 >> 6) << 4) | (e1 & 15), q1 = (e1 >> 4) & 3;
  const unsigned short* Au = (const unsigned short*)A;
  const unsigned short* Bu = (const unsigned short*)Bw;
  const unsigned short* Lu = Bu + (SPLIT ? WSZ_ : 0);
  for (int k0 = 0; k0 < C_; k0 += BK) {
    short8 a0 = *(const short8*)&Au[(size_t)(m0 + r0) * C_ + k0 + q0 * 8];
    short8 a1 = *(const short8*)&Au[(size_t)(m0 + r1) * C_ + k0 + q1 * 8];
    short8 b0 = *(const short8*)&Bu[(size_t)(n0 + r0) * C_ + k0 + q0 * 8];
    short8 b1, l0, l1;
    if constexpr (BN == 128)
      b1 = *(const short8*)&Bu[(size_t)(n0 + r1) * C_ + k0 + q1 * 8];
    if constexpr (SPLIT) {
      l0 = *(const short8*)&Lu[(size_t)(n0 + r0) * C_ + k0 + q0 * 8];
      if constexpr (BN == 128)
        l1 = *(const short8*)&Lu[(size_t)(n0 + r1) * C_ + k0 + q1 * 8];
    }
    __syncthreads();
    Asm[e0] = a0; Asm[e1] = a1;
    Bsm[e0] = b0;
    if constexpr (BN == 128) Bsm[e1] = b1;
    if constexpr (SPLIT) {
      Lsm[e0] = l0;
      if constexpr (BN == 128) Lsm[e1] = l1;
    }
    __syncthreads();
    short8 af[MT], bh[NT];
    #pragma unroll
    for (int mt = 0; mt < MT; ++mt) af[mt] = Asm[((wm >> 4) + mt) * 64 + lane];
    #pragma unroll
    for (int nt = 0; nt < NT; ++nt) bh[nt] = Bsm[((wn >> 4) + nt) * 64 + lane];
    #pragma unroll
    for (int mt = 0; mt < MT; ++mt)
      #pragma unroll
      for (int nt = 0; nt < NT; ++nt)
        acc[mt][nt] = __builtin_amdgcn_mfma_f32_16x16x32_bf16(
            af[mt], bh[nt], acc[mt][nt], 0, 0, 0);
    if constexpr (SPLIT) {
      short8 bl[NT];
      #pragma unroll
      for (int nt = 0; nt < NT; ++nt) bl[nt] = Lsm[((wn >> 4) + nt) * 64 + lane];
      #pragma unroll
      for (int mt = 0; mt < MT; ++mt)
        #pragma unroll
        for (int nt = 0; nt < NT; ++nt)
          acc[mt][nt] = __builtin_amdgcn_mfma_f32_16x16x32_bf16(
              af[mt], bl[nt], acc[mt][nt], 0, 0, 0);
    }
  }
  const int col = lane & 15, qr = lane >> 4;
  #pragma unroll
  for (int mt = 0; mt < MT; ++mt) {
    int mrow = m0 + wm + mt * 16 + qr * 4;
    #pragma unroll
    for (int nt = 0; nt < NT; ++nt) {
      int nc = n0 + wn + nt * 16 + col;
      #pragma unroll
      for (int r = 0; r < 4; ++r) {
        float v = acc[mt][nt][r];
        if (MODE == 1) v = v / (1.f + __expf(-v));
        if (MODE == 3) v = tanhf(v);
        size_t oi = (size_t)(mrow + r) * N + nc;
        if (MODE == 2) ((float*)O)[oi] = v;
        else           ((bf16*)O)[oi] = f2b(v);
      }
    }
  }
}

// ---------------------------------------------------------------------------
// mix_mfma: replaces the ds_read_b32-bound mix_all. Five K=32 GEMMs
// m_f = mix5[:, f*32:(f+1)*32] @ w2[f] done as MFMA (one 16x16x32 per tile
// per f), fused with the elementwise epilogue
//   x_f = x + (xshift - x) * (tm_f + m_f)   -> 5 bf16 outputs.
// Block = 64 rows x 64 cols, 4 waves (one 16-row band each). LDS stride
// padded to 200 bf16 (400B) -> 16B-aligned rows, 2-way-max bank aliasing.
// ---------------------------------------------------------------------------
__global__ __launch_bounds__(256) void mix_mfma_kernel(
    const bf16* __restrict__ mix5, const bf16* __restrict__ w2p,
    const float* __restrict__ x,
    const float* __restrict__ tmw, const float* __restrict__ tmk,
    const float* __restrict__ tmv, const float* __restrict__ tmr,
    const float* __restrict__ tmg,
    bf16* __restrict__ xw, bf16* __restrict__ xk, bf16* __restrict__ xv,
    bf16* __restrict__ xr, bf16* __restrict__ xg) {
  constexpr int LDP = 200;
  __shared__ __align__(16) unsigned short Asm[64 * LDP];
  __shared__ __align__(16) unsigned short Bsm[64 * LDP];
  const int tid = threadIdx.x;
  const int row0 = blockIdx.x * 64;
  const int col0 = blockIdx.y * 64;
  const unsigned short* Au = (const unsigned short*)mix5;
  const unsigned short* Bu = (const unsigned short*)w2p;
  #pragma unroll
  for (int e0 = 0; e0 < 64 * 20; e0 += 256) {
    int e = e0 + tid;
    int rr = e / 20, p = e - rr * 20;
    *(short8*)&Asm[rr * LDP + p * 8] =
        *(const short8*)&Au[(size_t)(row0 + rr) * 192 + p * 8];
    *(short8*)&Bsm[rr * LDP + p * 8] =
        *(const short8*)&Bu[(size_t)(col0 + rr) * 192 + p * 8];
  }
  __syncthreads();
  const int lane = tid & 63, wave = tid >> 6;
  const int fl = lane & 15, q = lane >> 4;
  short8 af[5];
  #pragma unroll
  for (int f = 0; f < 5; ++f)
    af[f] = *(const short8*)&Asm[(wave * 16 + fl) * LDP + f * 32 + q * 8];
  f32x4 acc[4][5] = {};
  #pragma unroll
  for (int nt = 0; nt < 4; ++nt)
    #pragma unroll
    for (int f = 0; f < 5; ++f) {
      short8 bfr = *(const short8*)&Bsm[(nt * 16 + fl) * LDP + f * 32 + q * 8];
      acc[nt][f] = __builtin_amdgcn_mfma_f32_16x16x32_bf16(
          af[f], bfr, acc[nt][f], 0, 0, 0);
    }
  // epilogue: C layout col = lane&15, row = (lane>>4)*4 + r
  #pragma unroll
  for (int nt = 0; nt < 4; ++nt) {
    int cc = col0 + nt * 16 + fl;
    float vw = tmw[cc], vk = tmk[cc], vv = tmv[cc], vr = tmr[cc],
          vg = tmg[cc];
    #pragma unroll
    for (int r = 0; r < 4; ++r) {
      int rr = row0 + wave * 16 + q * 4 + r;
      size_t idx = (size_t)rr * C_ + cc;
      float xc = x[idx];
      float xx = (((rr & (T_ - 1)) == 0) ? 0.f : x[idx - C_]) - xc;
      xw[idx] = f2b(xc + xx * (vw + acc[nt][0][r]));
      xk[idx] = f2b(xc + xx * (vk + acc[nt][1][r]));
      xv[idx] = f2b(xc + xx * (vv + acc[nt][2][r]));
      xr[idx] = f2b(xc + xx * (vr + acc[nt][3][r]));
      xg[idx] = f2b(xc + xx * (vg + acc[nt][4][r]));
    }
  }
}

// ---------------------------------------------------------------------------
// decay (unchanged, verified): w = td + h1 @ Wd2 (K=64); ee = exp(w) bf16.
// ---------------------------------------------------------------------------
__global__ __launch_bounds__(512) void decay_kernel(
    const bf16* __restrict__ h1, const float* __restrict__ wd2,
    const float* __restrict__ tdecay, bf16* __restrict__ ee) {
  __shared__ float Hs[8][64];
  int row0 = blockIdx.x * 8;
  {
    int e = threadIdx.x;
    Hs[e >> 6][e & 63] = b2f(h1[(size_t)(row0 + (e >> 6)) * 64 + (e & 63)]);
  }
  __syncthreads();
  int c = threadIdx.x;
  float acc[8] = {0.f,0.f,0.f,0.f,0.f,0.f,0.f,0.f};
  for (int j = 0; j < 64; ++j) {
    float wv = wd2[j * C_ + c];
    #pragma unroll
    for (int r = 0; r < 8; ++r) acc[r] += Hs[r][j] * wv;
  }
  float td = tdecay[c];
  #pragma unroll
  for (int r = 0; r < 8; ++r)
    ee[(size_t)(row0 + r) * C_ + c] = f2b(expf(td + acc[r]));
}

// ---------------------------------------------------------------------------
// WKV6 chunked scan — MFMA form (unchanged, verified round 9).
// ---------------------------------------------------------------------------
__global__ __launch_bounds__(64) void wkv_partial_mfma(
    const bf16* __restrict__ k, const bf16* __restrict__ v,
    const bf16* __restrict__ ee, float* __restrict__ st) {
  __shared__ __align__(16) char smem[17536];
  float* Lm  = (float*)smem;              // [65][32]
  bf16*  K2T = (bf16*)(smem + 8320);      // [32][72]
  bf16*  VT  = (bf16*)(smem + 12928);     // [32][72]
  int g = blockIdx.x;
  int bh = g >> 5, c = g & (NC_ - 1);
  int b = bh >> 4, h = bh & 15;
  int lane = threadIdx.x;
  size_t gbase = (size_t)b * T_ * C_ + (size_t)(c * CL_) * C_ + h * HS_;
  if (lane < 32) {
    int j = lane;
    float L = 0.f;
    for (int t = 0; t < CL_; ++t) {
      Lm[t * 32 + j] = L;
      L -= b2f(ee[gbase + (size_t)t * C_ + j]);
    }
    Lm[64 * 32 + j] = L;
  }
  __syncthreads();
  for (int it = 0; it < 32; ++it) {
    int t = it * 2 + (lane >> 5);
    int ch = lane & 31;
    size_t gi = gbase + (size_t)t * C_ + ch;
    float Lt1  = Lm[(t + 1) * 32 + ch];
    float Ltot = Lm[64 * 32 + ch];
    K2T[ch * 72 + t] = f2b(b2f(k[gi]) * __expf(Ltot - Lt1));
    VT [ch * 72 + t] = v[gi];
  }
  __syncthreads();
  const int fl = lane & 15, q = lane >> 4;
  f32x4 accS[2][2] = {};
  #pragma unroll
  for (int kc = 0; kc < 2; ++kc) {
    short8 av[2], bk[2];
    #pragma unroll
    for (int mt = 0; mt < 2; ++mt)
      av[mt] = *(const short8*)(VT + (mt * 16 + fl) * 72 + kc * 32 + q * 8);
    #pragma unroll
    for (int nt = 0; nt < 2; ++nt)
      bk[nt] = *(const short8*)(K2T + (nt * 16 + fl) * 72 + kc * 32 + q * 8);
    #pragma unroll
    for (int mt = 0; mt < 2; ++mt)
      #pragma unroll
      for (int nt = 0; nt < 2; ++nt)
        accS[mt][nt] = __builtin_amdgcn_mfma_f32_16x16x32_bf16(
            av[mt], bk[nt], accS[mt][nt], 0, 0, 0);
  }
  size_t sbase = (size_t)g * STF_;
  #pragma unroll
  for (int mt = 0; mt < 2; ++mt)
    #pragma unroll
    for (int nt = 0; nt < 2; ++nt)
      #pragma unroll
      for (int r = 0; r < 4; ++r)
        st[sbase + (size_t)(mt * 16 + q * 4 + r) * 32 + nt * 16 + fl] =
            accS[mt][nt][r];
  if (lane < 32) st[sbase + 1024 + lane] = __expf(Lm[64 * 32 + lane]);
}

__global__ __launch_bounds__(64) void wkv_stitch_kernel(float* __restrict__ st) {
  int bh = blockIdx.x;
  int lane = threadIdx.x;
  int i = lane & 31, half = lane >> 5;
  float R[16];
  #pragma unroll
  for (int jj = 0; jj < 16; ++jj) R[jj] = 0.f;
  for (int c = 0; c < NC_; ++c) {
    size_t s = ((size_t)bh * NC_ + c) * STF_;
    float* sp = st + s + i * 32 + (half << 4);
    float Sc[16];
    float4* sc4 = reinterpret_cast<float4*>(Sc);
    float4* sp4 = reinterpret_cast<float4*>(sp);
    #pragma unroll
    for (int q = 0; q < 4; ++q) sc4[q] = sp4[q];
    float Pj[16];
    #pragma unroll
    for (int jj = 0; jj < 16; ++jj) Pj[jj] = st[s + 1024 + (half << 4) + jj];
    float4* r4 = reinterpret_cast<float4*>(R);
    #pragma unroll
    for (int q = 0; q < 4; ++q) sp4[q] = r4[q];
    #pragma unroll
    for (int jj = 0; jj < 16; ++jj) R[jj] = fmaf(Pj[jj], R[jj], Sc[jj]);
  }
}

__global__ __launch_bounds__(64) void wkv_final_mfma(
    const bf16* __restrict__ r, const bf16* __restrict__ k,
    const bf16* __restrict__ v, const bf16* __restrict__ ee,
    const float* __restrict__ faaaa, const float* __restrict__ st,
    bf16* __restrict__ y) {
  __shared__ __align__(16) char smem[29440];
  float* Lm = (float*)smem;               // [65][32] — aliased by Pm later
  bf16*  Pm = (bf16*)smem;                // [64][72]
  bf16*  RA = (bf16*)(smem + 9216);       // [64][40]
  bf16*  Kd = (bf16*)(smem + 14336);      // [64][40]
  bf16*  VT = (bf16*)(smem + 19456);      // [32][72]
  bf16*  Sh = (bf16*)(smem + 24064);      // [32][40]
  bf16*  Sl = (bf16*)(smem + 26624);      // [32][40]
  float* bon = (float*)(smem + 29184);    // [64]
  int g = blockIdx.x;
  int bh = g >> 5, c = g & (NC_ - 1);
  int b = bh >> 4, h = bh & 15;
  int lane = threadIdx.x;
  size_t gbase = (size_t)b * T_ * C_ + (size_t)(c * CL_) * C_ + h * HS_;
  size_t sbase = (size_t)g * STF_;
  if (lane < 32) {
    int j = lane;
    float L = 0.f;
    for (int t = 0; t < CL_; ++t) {
      Lm[t * 32 + j] = L;
      L -= b2f(ee[gbase + (size_t)t * C_ + j]);
    }
    Lm[64 * 32 + j] = L;
  }
  for (int it = 0; it < 16; ++it) {
    int idx = it * 64 + lane;
    int i = idx >> 5, j = idx & 31;
    float s = st[sbase + idx];
    bf16 hi = f2b(s);
    Sh[i * 40 + j] = hi;
    Sl[i * 40 + j] = f2b(s - b2f(hi));
  }
  float u_j = faaaa[h * HS_ + (lane & 31)];
  __syncthreads();
  for (int it = 0; it < 32; ++it) {
    int t = it * 2 + (lane >> 5);
    int ch = lane & 31;
    size_t gi = gbase + (size_t)t * C_ + ch;
    float rv = b2f(r[gi]), kv = b2f(k[gi]);
    float Lt  = Lm[t * 32 + ch];
    float Lt1 = Lm[(t + 1) * 32 + ch];
    RA[t * 40 + ch] = f2b(rv * __expf(Lt));
    Kd[t * 40 + ch] = f2b(kv * __expf(-Lt1));
    VT[ch * 72 + t] = v[gi];
    float pb = rv * u_j * kv;
    pb += __shfl_xor(pb, 1); pb += __shfl_xor(pb, 2);
    pb += __shfl_xor(pb, 4); pb += __shfl_xor(pb, 8);
    pb += __shfl_xor(pb, 16);
    if (ch == 0) bon[t] = pb;
  }
  __syncthreads();
  const int fl = lane & 15, q = lane >> 4;
  short8 afr[4];
  #pragma unroll
  for (int mt = 0; mt < 4; ++mt)
    afr[mt] = *(const short8*)(RA + (mt * 16 + fl) * 40 + q * 8);
  f32x4 accY[4][2] = {};
  {
    short8 sh[2], sl[2];
    #pragma unroll
    for (int nt = 0; nt < 2; ++nt) {
      sh[nt] = *(const short8*)(Sh + (nt * 16 + fl) * 40 + q * 8);
      sl[nt] = *(const short8*)(Sl + (nt * 16 + fl) * 40 + q * 8);
    }
    #pragma unroll
    for (int mt = 0; mt < 4; ++mt)
      #pragma unroll
      for (int nt = 0; nt < 2; ++nt) {
        accY[mt][nt] = __builtin_amdgcn_mfma_f32_16x16x32_bf16(
            afr[mt], sh[nt], accY[mt][nt], 0, 0, 0);
        accY[mt][nt] = __builtin_amdgcn_mfma_f32_16x16x32_bf16(
            afr[mt], sl[nt], accY[mt][nt], 0, 0, 0);
      }
  }
  f32x4 accP[4][4] = {};
  {
    short8 bk[4];
    #pragma unroll
    for (int s4 = 0; s4 < 4; ++s4)
      bk[s4] = *(const short8*)(Kd + (s4 * 16 + fl) * 40 + q * 8);
    #pragma unroll
    for (int mt = 0; mt < 4; ++mt)
      #pragma unroll
      for (int s4 = 0; s4 < 4; ++s4)
        accP[mt][s4] = __builtin_amdgcn_mfma_f32_16x16x32_bf16(
            afr[mt], bk[s4], accP[mt][s4], 0, 0, 0);
  }
  __syncthreads();
  #pragma unroll
  for (int mt = 0; mt < 4; ++mt)
    #pragma unroll
    for (int s4 = 0; s4 < 4; ++s4)
      #pragma unroll
      for (int rr = 0; rr < 4; ++rr) {
        int t = mt * 16 + q * 4 + rr;
        int s = s4 * 16 + fl;
        float pv = accP[mt][s4][rr];
        float bv = bon[t];
        pv = (s < t) ? pv : ((s == t) ? bv : 0.f);
        Pm[t * 72 + s] = f2b(pv);
      }
  __syncthreads();
  {
    short8 bv[2][2];
    #pragma unroll
    for (int nt = 0; nt < 2; ++nt)
      #pragma unroll
      for (int kc = 0; kc < 2; ++kc)
        bv[nt][kc] = *(const short8*)(VT + (nt * 16 + fl) * 72 + kc * 32 + q * 8);
    #pragma unroll
    for (int mt = 0; mt < 4; ++mt)
      #pragma unroll
      for (int kc = 0; kc < 2; ++kc) {
        short8 ap = *(const short8*)(Pm + (mt * 16 + fl) * 72 + kc * 32 + q * 8);
        #pragma unroll
        for (int nt = 0; nt < 2; ++nt)
          accY[mt][nt] = __builtin_amdgcn_mfma_f32_16x16x32_bf16(
              ap, bv[nt][kc], accY[mt][nt], 0, 0, 0);
      }
  }
  #pragma unroll
  for (int mt = 0; mt < 4; ++mt)
    #pragma unroll
    for (int nt = 0; nt < 2; ++nt)
      #pragma unroll
      for (int rr = 0; rr < 4; ++rr) {
        int t = mt * 16 + q * 4 + rr;
        int i = nt * 16 + fl;
        y[gbase + (size_t)t * C_ + i] = f2b(accY[mt][nt][rr]);
      }
}

// ---------------------------------------------------------------------------
// groupnorm over HS=32, * ln_w + ln_b, * silu(g) -> z bf16  (unchanged)
// ---------------------------------------------------------------------------
__global__ __launch_bounds__(256) void gnorm_kernel(
    const bf16* __restrict__ y, const bf16* __restrict__ g,
    const float* __restrict__ lnw, const float* __restrict__ lnb,
    bf16* __restrict__ z) {
  int grp = blockIdx.x * 8 + (threadIdx.x >> 5);
  int i = threadIdx.x & 31;
  int token = grp >> 4, h = grp & 15;
  size_t idx = (size_t)token * C_ + h * HS_ + i;
  float yv = b2f(y[idx]);
  float mu = yv;
  mu += __shfl_xor(mu, 1); mu += __shfl_xor(mu, 2); mu += __shfl_xor(mu, 4);
  mu += __shfl_xor(mu, 8); mu += __shfl_xor(mu, 16);
  mu *= (1.f / 32.f);
  float d = yv - mu;
  float var = d * d;
  var += __shfl_xor(var, 1); var += __shfl_xor(var, 2); var += __shfl_xor(var, 4);
  var += __shfl_xor(var, 8); var += __shfl_xor(var, 16);
  var *= (1.f / 32.f);
  float yn = d * rsqrtf(var + 1e-5f);
  int c = h * HS_ + i;
  float outv = (yn * lnw[c] + lnb[c]) * b2f(g[idx]);
  z[idx] = f2b(outv);
}

// ---------------------------------------------------------------------------
extern "C" void kernel_launch(void* const* d_in, const int* in_sizes, int n_in,
                              void* d_out, int out_size, void* d_ws, size_t ws_size,
                              hipStream_t stream) {
  (void)in_sizes; (void)n_in; (void)out_size; (void)ws_size;
  const float* x      = (const float*)d_in[0];
  const float* tmx    = (const float*)d_in[1];
  const float* tmw    = (const float*)d_in[2];
  const float* tmk    = (const float*)d_in[3];
  const float* tmv    = (const float*)d_in[4];
  const float* tmr    = (const float*)d_in[5];
  const float* tmg    = (const float*)d_in[6];
  const float* w1     = (const float*)d_in[7];
  const float* w2     = (const float*)d_in[8];
  const float* tdecay = (const float*)d_in[9];
  const float* wd1    = (const float*)d_in[10];
  const float* wd2    = (const float*)d_in[11];
  const float* faaaa  = (const float*)d_in[12];
  const float* Wr     = (const float*)d_in[13];
  const float* Wk     = (const float*)d_in[14];
  const float* Wv     = (const float*)d_in[15];
  const float* Wg     = (const float*)d_in[16];
  const float* Wo     = (const float*)d_in[17];
  const float* lnw    = (const float*)d_in[18];
  const float* lnb    = (const float*)d_in[19];
  float* out = (float*)d_out;

  // workspace layout — 6 x 16MB slots + st + weights; peak ~118 MB
  // (<= 119.25 MB proven safe in rounds 3/4 A-B)
  char* w8 = (char*)d_ws;
  const size_t MB = 1024ull * 1024ull;
  bf16* S0 = (bf16*)(w8 +  0 * MB);  // xxx -> xw -> ee
  bf16* S1 = (bf16*)(w8 + 16 * MB);  // xk -> vb
  bf16* S2 = (bf16*)(w8 + 32 * MB);  // xv -> gb
  bf16* S3 = (bf16*)(w8 + 48 * MB);  // xr -> kb -> zb
  bf16* S4 = (bf16*)(w8 + 64 * MB);  // xg -> y
  bf16* S5 = (bf16*)(w8 + 80 * MB);  // mix5p+h1 -> rb
  float* st = (float*)(w8 + 96 * MB);            // 16.5 MB
  char* wreg = w8 + 112 * MB + 512 * 1024;       // weights at 112.5 MB
  bf16* Wrb  = (bf16*)(wreg);
  bf16* Wkb  = Wrb + 2 * WSZ_;
  bf16* Wvb  = Wkb + 2 * WSZ_;
  bf16* Wgb  = Wvb + 2 * WSZ_;
  bf16* Wob  = Wgb + 2 * WSZ_;
  bf16* w1p  = Wob + 2 * WSZ_;                   // [192][512]
  bf16* wd1p = w1p + 192 * 512;                  // [64][512]
  bf16* w2p  = wd1p + 64 * 512;                  // [512][192]
  bf16* mix5p = S5;                              // [16384][192], 6 MB
  bf16* h1    = S5 + (size_t)BT_ * 192;          // [16384][64],  2 MB

  // 1. fused prep: xxx (S0) + weight splits + w1/wd1/w2 transpose
  prep_combo_kernel<<<PREP_N_, 256, 0, stream>>>(
      x, tmx, Wr, Wk, Wv, Wg, Wo, w1, wd1, w2,
      S0, Wrb, Wkb, Wvb, Wgb, Wob, w1p, wd1p, w2p);
  // 2. mix5p = tanh(xxx @ w1p^T)
  mfma_gemm_kernel<64, 3, 0><<<dim3(128, 3), 256, 0, stream>>>(S0, w1p, mix5p, 192);
  // 3. all five mixed activations in one MFMA pass (xxx dead -> xw over S0)
  mix_mfma_kernel<<<dim3(BT_ / 64, 8), 256, 0, stream>>>(
      mix5p, w2p, x, tmw, tmk, tmv, tmr, tmg, S0, S1, S2, S3, S4);
  // 4. h1 = tanh(xw @ wd1^T);  5. ee = exp(td + h1 @ wd2)  (ee over xw slot)
  mfma_gemm_kernel<64, 3, 0><<<dim3(128, 1), 256, 0, stream>>>(S0, wd1p, h1, 64);
  decay_kernel<<<BT_ / 8, 512, 0, stream>>>(h1, wd2, tdecay, S0);
  // 6-9. projections (split weights)
  dim3 gg(128, 4);
  mfma_gemm_kernel<128, 0, 1><<<gg, 256, 0, stream>>>(S3, Wrb, S5, C_);  // xr->rb(S5)
  mfma_gemm_kernel<128, 0, 1><<<gg, 256, 0, stream>>>(S1, Wkb, S3, C_);  // xk->kb(S3)
  mfma_gemm_kernel<128, 0, 1><<<gg, 256, 0, stream>>>(S2, Wvb, S1, C_);  // xv->vb(S1)
  mfma_gemm_kernel<128, 1, 1><<<gg, 256, 0, stream>>>(S4, Wgb, S2, C_);  // xg->gb(S2), silu
  // 10-12. chunk-parallel WKV6 scan (MFMA form)
  wkv_partial_mfma<<<B_ * H_ * NC_, 64, 0, stream>>>(S3, S1, S0, st);
  wkv_stitch_kernel<<<B_ * H_, 64, 0, stream>>>(st);
  wkv_final_mfma<<<B_ * H_ * NC_, 64, 0, stream>>>(S5, S3, S1, S0, faaaa, st, S4);
  // 13. groupnorm * g -> zb (S3; kb dead)   14. output projection (fp32)
  gnorm_kernel<<<(BT_ * H_) / 8, 256, 0, stream>>>(S4, S2, lnw, lnb, S3);
  mfma_gemm_kernel<128, 2, 1><<<gg, 256, 0, stream>>>(S3, Wob, out, C_);
}

// Round 2
// 446.687 us; speedup vs baseline: 1.2447x; 1.1214x over previous
//
#include <hip/hip_runtime.h>
#include <hip/hip_bf16.h>

#define B_ 8
#define T_ 2048
#define C_ 512
#define H_ 16
#define HS_ 32
#define BT_ (B_*T_)   // 16384 tokens
#define CL_ 64        // scan chunk length
#define NC_ (T_/CL_)  // 32 chunks
#define STF_ 1056     // floats per (bh,chunk) state: 1024 S + 32 P
#define WSZ_ 262144   // elements per 512x512 weight (2^18)

typedef __hip_bfloat16 bf16;
typedef __attribute__((ext_vector_type(8))) short short8;
typedef __attribute__((ext_vector_type(4))) float f32x4;

__device__ __forceinline__ float b2f(bf16 v) { return __bfloat162float(v); }
__device__ __forceinline__ bf16 f2b(float v) { return __float2bfloat16(v); }

// ---------------------------------------------------------------------------
// prep_combo: one launch does (a) xxx = x + (xshift-x)*maa_x, (b) hi/lo bf16
// split of the five 512x512 weights, (c) transpose+pad w1 -> [192][512] and
// wd1 -> [64][512], (d) transpose+pad w2 -> [512][192] bf16 for mix_mfma.
// ---------------------------------------------------------------------------
__global__ __launch_bounds__(256) void prep_combo_kernel(
    const float* __restrict__ x, const float* __restrict__ tmx,
    const float* __restrict__ Wr, const float* __restrict__ Wk,
    const float* __restrict__ Wv, const float* __restrict__ Wg,
    const float* __restrict__ Wo, const float* __restrict__ w1,
    const float* __restrict__ wd1, const float* __restrict__ w2,
    bf16* __restrict__ xxx, bf16* __restrict__ Wrb, bf16* __restrict__ Wkb,
    bf16* __restrict__ Wvb, bf16* __restrict__ Wgb, bf16* __restrict__ Wob,
    bf16* __restrict__ w1p, bf16* __restrict__ wd1p, bf16* __restrict__ w2p) {
  int idx = blockIdx.x * 256 + threadIdx.x;
  if (idx < BT_ * C_) {                       // token-shift mix input
    int c = idx & (C_ - 1);
    int t = (idx >> 9) & (T_ - 1);
    float xc = x[idx];
    float xp = (t == 0) ? 0.f : x[idx - C_];
    xxx[idx] = f2b(xc + (xp - xc) * tmx[c]);
    return;
  }
  idx -= BT_ * C_;
  if (idx < 5 * WSZ_) {                       // weight hi/lo split
    int w = idx >> 18;
    int i = idx & (WSZ_ - 1);
    const float* src = (w == 0) ? Wr : (w == 1) ? Wk : (w == 2) ? Wv
                     : (w == 3) ? Wg : Wo;
    bf16* dst = (w == 0) ? Wrb : (w == 1) ? Wkb : (w == 2) ? Wvb
              : (w == 3) ? Wgb : Wob;
    float s = src[i];
    bf16 hi = f2b(s);
    dst[i] = hi;
    dst[WSZ_ + i] = f2b(s - b2f(hi));
    return;
  }
  idx -= 5 * WSZ_;
  if (idx < 192 * 512) {                      // w1^T padded to 192 rows
    int n = idx >> 9, k = idx & (C_ - 1);
    w1p[idx] = f2b(n < 160 ? w1[k * 160 + n] : 0.f);
    return;
  }
  idx -= 192 * 512;
  if (idx < 64 * 512) {                       // wd1^T [64][512]
    int n = idx >> 9, k = idx & (C_ - 1);
    wd1p[idx] = f2b(wd1[k * 64 + n]);
    return;
  }
  idx -= 64 * 512;
  {                                           // w2^T padded [512][192]
    int c = idx / 192, n = idx - c * 192;     // n = f*32+d
    w2p[idx] = f2b(n < 160 ? w2[(size_t)n * C_ + c] : 0.f);
  }
}
#define PREP_N_ ((BT_*C_ + 5*WSZ_ + 192*512 + 64*512 + 512*192) / 256) // 38784

// ---------------------------------------------------------------------------
// MFMA GEMM: O = act(A @ Bw^T). BM=128, BK=32, 256 thr. (verified round 8)
// MODE: 0 bf16; 1 bf16+silu; 2 fp32; 3 bf16+tanh.  N = output stride.
// ---------------------------------------------------------------------------
template<int BN, int MODE, int SPLIT>
__global__ __launch_bounds__(256) void mfma_gemm_kernel(
    const bf16* __restrict__ A, const bf16* __restrict__ Bw,
    void* __restrict__ O, int N) {
  constexpr int BM = 128, BK = 32;
  constexpr int AE = BM * BK / 8;
  constexpr int BE = BN * BK / 8;
  __shared__ short8 Asm[AE];
  __shared__ short8 Bsm[BE];
  __shared__ short8 Lsm[SPLIT ? BE : 1];
  const int tid = threadIdx.x;
  const int lane = tid & 63;
  const int wave = tid >> 6;
  const int m0 = blockIdx.x * BM;
  const int n0 = blockIdx.y * BN;
  const int wm = (BN == 128) ? (wave >> 1) * 64 : wave * 32;
  const int wn = (BN == 128) ? (wave & 1) * 64 : 0;
  constexpr int MT = (BN == 128) ? 4 : 2;
  constexpr int NT = 4;
  f32x4 acc[MT][NT] = {};
  const int e0 = tid, e1 = tid + 256;
  const int r0 = ((e0 >> 6) << 4) | (e0 & 15), q0 = (e0 >> 4) & 3;
  const int r1 = ((e1 >> 6) << 4) | (e1 & 15), q1 = (e1 >> 4) & 3;
  const unsigned short* Au = (const unsigned short*)A;
  const unsigned short* Bu = (const unsigned short*)Bw;
  const unsigned short* Lu = Bu + (SPLIT ? WSZ_ : 0);
  for (int k0 = 0; k0 < C_; k0 += BK) {
    short8 a0 = *(const short8*)&Au[(size_t)(m0 + r0) * C_ + k0 + q0 * 8];
    short8 a1 = *(const short8*)&Au[(size_t)(m0 + r1) * C_ + k0 + q1 * 8];
    short8 b0 = *(const short8*)&Bu[(size_t)(n0 + r0) * C_ + k0 + q0 * 8];
    short8 b1, l0, l1;
    if constexpr (BN == 128)
      b1 = *(const short8*)&Bu[(size_t)(n0 + r1) * C_ + k0 + q1 * 8];
    if constexpr (SPLIT) {
      l0 = *(const short8*)&Lu[(size_t)(n0 + r0) * C_ + k0 + q0 * 8];
      if constexpr (BN == 128)
        l1 = *(const short8*)&Lu[(size_t)(n0 + r1) * C_ + k0 + q1 * 8];
    }
    __syncthreads();
    Asm[e0] = a0; Asm[e1] = a1;
    Bsm[e0] = b0;
    if constexpr (BN == 128) Bsm[e1] = b1;
    if constexpr (SPLIT) {
      Lsm[e0] = l0;
      if constexpr (BN == 128) Lsm[e1] = l1;
    }
    __syncthreads();
    short8 af[MT], bh[NT];
    #pragma unroll
    for (int mt = 0; mt < MT; ++mt) af[mt] = Asm[((wm >> 4) + mt) * 64 + lane];
    #pragma unroll
    for (int nt = 0; nt < NT; ++nt) bh[nt] = Bsm[((wn >> 4) + nt) * 64 + lane];
    #pragma unroll
    for (int mt = 0; mt < MT; ++mt)
      #pragma unroll
      for (int nt = 0; nt < NT; ++nt)
        acc[mt][nt] = __builtin_amdgcn_mfma_f32_16x16x32_bf16(
            af[mt], bh[nt], acc[mt][nt], 0, 0, 0);
    if constexpr (SPLIT) {
      short8 bl[NT];
      #pragma unroll
      for (int nt = 0; nt < NT; ++nt) bl[nt] = Lsm[((wn >> 4) + nt) * 64 + lane];
      #pragma unroll
      for (int mt = 0; mt < MT; ++mt)
        #pragma unroll
        for (int nt = 0; nt < NT; ++nt)
          acc[mt][nt] = __builtin_amdgcn_mfma_f32_16x16x32_bf16(
              af[mt], bl[nt], acc[mt][nt], 0, 0, 0);
    }
  }
  const int col = lane & 15, qr = lane >> 4;
  #pragma unroll
  for (int mt = 0; mt < MT; ++mt) {
    int mrow = m0 + wm + mt * 16 + qr * 4;
    #pragma unroll
    for (int nt = 0; nt < NT; ++nt) {
      int nc = n0 + wn + nt * 16 + col;
      #pragma unroll
      for (int r = 0; r < 4; ++r) {
        float v = acc[mt][nt][r];
        if (MODE == 1) v = v / (1.f + __expf(-v));
        if (MODE == 3) v = tanhf(v);
        size_t oi = (size_t)(mrow + r) * N + nc;
        if (MODE == 2) ((float*)O)[oi] = v;
        else           ((bf16*)O)[oi] = f2b(v);
      }
    }
  }
}

// ---------------------------------------------------------------------------
// mix_mfma (verified round 0 of this session): five K=32 GEMMs via MFMA
// fused with the elementwise epilogue x_f = x + (xshift-x)*(tm_f + m_f).
// ---------------------------------------------------------------------------
__global__ __launch_bounds__(256) void mix_mfma_kernel(
    const bf16* __restrict__ mix5, const bf16* __restrict__ w2p,
    const float* __restrict__ x,
    const float* __restrict__ tmw, const float* __restrict__ tmk,
    const float* __restrict__ tmv, const float* __restrict__ tmr,
    const float* __restrict__ tmg,
    bf16* __restrict__ xw, bf16* __restrict__ xk, bf16* __restrict__ xv,
    bf16* __restrict__ xr, bf16* __restrict__ xg) {
  constexpr int LDP = 200;
  __shared__ __align__(16) unsigned short Asm[64 * LDP];
  __shared__ __align__(16) unsigned short Bsm[64 * LDP];
  const int tid = threadIdx.x;
  const int row0 = blockIdx.x * 64;
  const int col0 = blockIdx.y * 64;
  const unsigned short* Au = (const unsigned short*)mix5;
  const unsigned short* Bu = (const unsigned short*)w2p;
  #pragma unroll
  for (int e0 = 0; e0 < 64 * 20; e0 += 256) {
    int e = e0 + tid;
    int rr = e / 20, p = e - rr * 20;
    *(short8*)&Asm[rr * LDP + p * 8] =
        *(const short8*)&Au[(size_t)(row0 + rr) * 192 + p * 8];
    *(short8*)&Bsm[rr * LDP + p * 8] =
        *(const short8*)&Bu[(size_t)(col0 + rr) * 192 + p * 8];
  }
  __syncthreads();
  const int lane = tid & 63, wave = tid >> 6;
  const int fl = lane & 15, q = lane >> 4;
  short8 af[5];
  #pragma unroll
  for (int f = 0; f < 5; ++f)
    af[f] = *(const short8*)&Asm[(wave * 16 + fl) * LDP + f * 32 + q * 8];
  f32x4 acc[4][5] = {};
  #pragma unroll
  for (int nt = 0; nt < 4; ++nt)
    #pragma unroll
    for (int f = 0; f < 5; ++f) {
      short8 bfr = *(const short8*)&Bsm[(nt * 16 + fl) * LDP + f * 32 + q * 8];
      acc[nt][f] = __builtin_amdgcn_mfma_f32_16x16x32_bf16(
          af[f], bfr, acc[nt][f], 0, 0, 0);
    }
  #pragma unroll
  for (int nt = 0; nt < 4; ++nt) {
    int cc = col0 + nt * 16 + fl;
    float vw = tmw[cc], vk = tmk[cc], vv = tmv[cc], vr = tmr[cc],
          vg = tmg[cc];
    #pragma unroll
    for (int r = 0; r < 4; ++r) {
      int rr = row0 + wave * 16 + q * 4 + r;
      size_t idx = (size_t)rr * C_ + cc;
      float xc = x[idx];
      float xx = (((rr & (T_ - 1)) == 0) ? 0.f : x[idx - C_]) - xc;
      xw[idx] = f2b(xc + xx * (vw + acc[nt][0][r]));
      xk[idx] = f2b(xc + xx * (vk + acc[nt][1][r]));
      xv[idx] = f2b(xc + xx * (vv + acc[nt][2][r]));
      xr[idx] = f2b(xc + xx * (vr + acc[nt][3][r]));
      xg[idx] = f2b(xc + xx * (vg + acc[nt][4][r]));
    }
  }
}

// ---------------------------------------------------------------------------
// decay (unchanged, verified): w = td + h1 @ Wd2 (K=64); ee = exp(w) bf16.
// ---------------------------------------------------------------------------
__global__ __launch_bounds__(512) void decay_kernel(
    const bf16* __restrict__ h1, const float* __restrict__ wd2,
    const float* __restrict__ tdecay, bf16* __restrict__ ee) {
  __shared__ float Hs[8][64];
  int row0 = blockIdx.x * 8;
  {
    int e = threadIdx.x;
    Hs[e >> 6][e & 63] = b2f(h1[(size_t)(row0 + (e >> 6)) * 64 + (e & 63)]);
  }
  __syncthreads();
  int c = threadIdx.x;
  float acc[8] = {0.f,0.f,0.f,0.f,0.f,0.f,0.f,0.f};
  for (int j = 0; j < 64; ++j) {
    float wv = wd2[j * C_ + c];
    #pragma unroll
    for (int r = 0; r < 8; ++r) acc[r] += Hs[r][j] * wv;
  }
  float td = tdecay[c];
  #pragma unroll
  for (int r = 0; r < 8; ++r)
    ee[(size_t)(row0 + r) * C_ + c] = f2b(expf(td + acc[r]));
}

// ---------------------------------------------------------------------------
// WKV6 chunked scan — 4-wave form. Each block = one (b,h,chunk); wave w owns
// t-band [w*16, w*16+16). ee tile preloaded to LDS (coalesced) so the serial
// prefix scan runs on LDS latency; r/k/v preloaded to regs before the scan
// barrier so HBM latency hides under it.
// ---------------------------------------------------------------------------
__global__ __launch_bounds__(256) void wkv_partial_mfma(
    const bf16* __restrict__ k, const bf16* __restrict__ v,
    const bf16* __restrict__ ee, float* __restrict__ st) {
  __shared__ __align__(16) char smem[17536];
  float* Lm  = (float*)smem;              // [65][32] floats, 8320 B
  bf16*  K2T = (bf16*)(smem + 8320);      // [32][72]
  bf16*  VT  = (bf16*)(smem + 12928);     // [32][72]
  bf16*  Eb  = K2T;                       // [64][32] scratch (dead pre-stage)
  int g = blockIdx.x;
  int bh = g >> 5, c = g & (NC_ - 1);
  int b = bh >> 4, h = bh & 15;
  const int tid = threadIdx.x;
  const int lane = tid & 63, wave = tid >> 6;
  const int ch = lane & 31, th = lane >> 5;
  size_t gbase = (size_t)b * T_ * C_ + (size_t)(c * CL_) * C_ + h * HS_;
  #pragma unroll
  for (int it = 0; it < 8; ++it) {
    int e = it * 256 + tid;
    Eb[e] = ee[gbase + (size_t)(e >> 5) * C_ + (e & 31)];
  }
  float kv[8]; bf16 vv[8];
  #pragma unroll
  for (int it = 0; it < 8; ++it) {
    int t = wave * 16 + it * 2 + th;
    size_t gi = gbase + (size_t)t * C_ + ch;
    kv[it] = b2f(k[gi]);
    vv[it] = v[gi];
  }
  __syncthreads();
  if (tid < 32) {
    float L = 0.f;
    for (int t = 0; t < CL_; ++t) {
      Lm[t * 32 + tid] = L;
      L -= b2f(Eb[t * 32 + tid]);
    }
    Lm[64 * 32 + tid] = L;
  }
  __syncthreads();
  float Ltot = Lm[64 * 32 + ch];
  #pragma unroll
  for (int it = 0; it < 8; ++it) {
    int t = wave * 16 + it * 2 + th;
    float Lt1 = Lm[(t + 1) * 32 + ch];
    K2T[ch * 72 + t] = f2b(kv[it] * __expf(Ltot - Lt1));
    VT [ch * 72 + t] = vv[it];
  }
  __syncthreads();
  const int fl = lane & 15, q = lane >> 4;
  const int mt = wave >> 1, nt = wave & 1;
  f32x4 accS = {};
  #pragma unroll
  for (int kc = 0; kc < 2; ++kc) {
    short8 av = *(const short8*)(VT + (mt * 16 + fl) * 72 + kc * 32 + q * 8);
    short8 bk = *(const short8*)(K2T + (nt * 16 + fl) * 72 + kc * 32 + q * 8);
    accS = __builtin_amdgcn_mfma_f32_16x16x32_bf16(av, bk, accS, 0, 0, 0);
  }
  size_t sbase = (size_t)g * STF_;
  #pragma unroll
  for (int r = 0; r < 4; ++r)
    st[sbase + (size_t)(mt * 16 + q * 4 + r) * 32 + nt * 16 + fl] = accS[r];
  if (tid < 32) st[sbase + 1024 + tid] = __expf(Lm[64 * 32 + tid]);
}

__global__ __launch_bounds__(64) void wkv_stitch_kernel(float* __restrict__ st) {
  int bh = blockIdx.x;
  int lane = threadIdx.x;
  int i = lane & 31, half = lane >> 5;
  float R[16];
  #pragma unroll
  for (int jj = 0; jj < 16; ++jj) R[jj] = 0.f;
  for (int c = 0; c < NC_; ++c) {
    size_t s = ((size_t)bh * NC_ + c) * STF_;
    float* sp = st + s + i * 32 + (half << 4);
    float Sc[16];
    float4* sc4 = reinterpret_cast<float4*>(Sc);
    float4* sp4 = reinterpret_cast<float4*>(sp);
    #pragma unroll
    for (int q = 0; q < 4; ++q) sc4[q] = sp4[q];
    float Pj[16];
    #pragma unroll
    for (int jj = 0; jj < 16; ++jj) Pj[jj] = st[s + 1024 + (half << 4) + jj];
    float4* r4 = reinterpret_cast<float4*>(R);
    #pragma unroll
    for (int q = 0; q < 4; ++q) sp4[q] = r4[q];
    #pragma unroll
    for (int jj = 0; jj < 16; ++jj) R[jj] = fmaf(Pj[jj], R[jj], Sc[jj]);
  }
}

// ---------------------------------------------------------------------------
// wkv_final: 4-wave + fused groupnorm. Wave w owns t-band [w*16, w*16+16):
// stages its band, computes its accY/accP tiles, writes its Pm rows, does
// its PV MFMAs, then normalizes each output row in-register (32 channels
// live across 16 lanes x 2 regs -> 4 shfl_xor) and writes z directly.
// ---------------------------------------------------------------------------
__global__ __launch_bounds__(256) void wkv_final_mfma(
    const bf16* __restrict__ r, const bf16* __restrict__ k,
    const bf16* __restrict__ v, const bf16* __restrict__ ee,
    const float* __restrict__ faaaa, const float* __restrict__ st,
    const bf16* __restrict__ gg, const float* __restrict__ lnw,
    const float* __restrict__ lnb, bf16* __restrict__ z) {
  __shared__ __align__(16) char smem[29440];
  float* Lm = (float*)smem;               // [65][32] — aliased by Pm later
  bf16*  Pm = (bf16*)smem;                // [64][72]
  bf16*  RA = (bf16*)(smem + 9216);       // [64][40]
  bf16*  Kd = (bf16*)(smem + 14336);      // [64][40]
  bf16*  VT = (bf16*)(smem + 19456);      // [32][72]
  bf16*  Eb = VT;                         // [64][32] scratch (dead pre-stage)
  bf16*  Sh = (bf16*)(smem + 24064);      // [32][40]
  bf16*  Sl = (bf16*)(smem + 26624);      // [32][40]
  float* bon = (float*)(smem + 29184);    // [64]
  int g = blockIdx.x;
  int bh = g >> 5, c = g & (NC_ - 1);
  int b = bh >> 4, h = bh & 15;
  const int tid = threadIdx.x;
  const int lane = tid & 63, wave = tid >> 6;
  const int ch = lane & 31, th = lane >> 5;
  size_t gbase = (size_t)b * T_ * C_ + (size_t)(c * CL_) * C_ + h * HS_;
  size_t sbase = (size_t)g * STF_;
  // ee tile -> LDS scratch (coalesced), S -> Sh/Sl, r/k/v -> regs
  #pragma unroll
  for (int it = 0; it < 8; ++it) {
    int e = it * 256 + tid;
    Eb[e] = ee[gbase + (size_t)(e >> 5) * C_ + (e & 31)];
  }
  #pragma unroll
  for (int it = 0; it < 4; ++it) {
    int idx = it * 256 + tid;
    int i = idx >> 5, j = idx & 31;
    float s = st[sbase + idx];
    bf16 hi = f2b(s);
    Sh[i * 40 + j] = hi;
    Sl[i * 40 + j] = f2b(s - b2f(hi));
  }
  float rv[8], kv[8]; bf16 vv[8];
  #pragma unroll
  for (int it = 0; it < 8; ++it) {
    int t = wave * 16 + it * 2 + th;
    size_t gi = gbase + (size_t)t * C_ + ch;
    rv[it] = b2f(r[gi]); kv[it] = b2f(k[gi]); vv[it] = v[gi];
  }
  __syncthreads();
  // serial prefix scan on LDS latency only
  if (tid < 32) {
    float L = 0.f;
    for (int t = 0; t < CL_; ++t) {
      Lm[t * 32 + tid] = L;
      L -= b2f(Eb[t * 32 + tid]);
    }
    Lm[64 * 32 + tid] = L;
  }
  __syncthreads();
  float u_j = faaaa[h * HS_ + ch];
  #pragma unroll
  for (int it = 0; it < 8; ++it) {
    int t = wave * 16 + it * 2 + th;
    float Lt  = Lm[t * 32 + ch];
    float Lt1 = Lm[(t + 1) * 32 + ch];
    RA[t * 40 + ch] = f2b(rv[it] * __expf(Lt));
    Kd[t * 40 + ch] = f2b(kv[it] * __expf(-Lt1));
    VT[ch * 72 + t] = vv[it];
    float pb = rv[it] * u_j * kv[it];
    pb += __shfl_xor(pb, 1); pb += __shfl_xor(pb, 2);
    pb += __shfl_xor(pb, 4); pb += __shfl_xor(pb, 8);
    pb += __shfl_xor(pb, 16);
    if (ch == 0) bon[t] = pb;
  }
  __syncthreads();
  const int fl = lane & 15, q = lane >> 4;
  short8 afr = *(const short8*)(RA + (wave * 16 + fl) * 40 + q * 8);
  f32x4 accY[2] = {};
  #pragma unroll
  for (int nt = 0; nt < 2; ++nt) {
    short8 sh = *(const short8*)(Sh + (nt * 16 + fl) * 40 + q * 8);
    short8 sl = *(const short8*)(Sl + (nt * 16 + fl) * 40 + q * 8);
    accY[nt] = __builtin_amdgcn_mfma_f32_16x16x32_bf16(afr, sh, accY[nt], 0, 0, 0);
    accY[nt] = __builtin_amdgcn_mfma_f32_16x16x32_bf16(afr, sl, accY[nt], 0, 0, 0);
  }
  f32x4 accP[4] = {};
  #pragma unroll
  for (int s4 = 0; s4 < 4; ++s4) {
    short8 bk = *(const short8*)(Kd + (s4 * 16 + fl) * 40 + q * 8);
    accP[s4] = __builtin_amdgcn_mfma_f32_16x16x32_bf16(afr, bk, accP[s4], 0, 0, 0);
  }
  // write own Pm band (Lm dead: last read was pre-MFMA barrier)
  #pragma unroll
  for (int s4 = 0; s4 < 4; ++s4)
    #pragma unroll
    for (int rr = 0; rr < 4; ++rr) {
      int t = wave * 16 + q * 4 + rr;
      int s = s4 * 16 + fl;
      float pv = accP[s4][rr];
      float bv = bon[t];
      pv = (s < t) ? pv : ((s == t) ? bv : 0.f);
      Pm[t * 72 + s] = f2b(pv);
    }
  __syncthreads();
  #pragma unroll
  for (int kc = 0; kc < 2; ++kc) {
    short8 ap = *(const short8*)(Pm + (wave * 16 + fl) * 72 + kc * 32 + q * 8);
    #pragma unroll
    for (int nt = 0; nt < 2; ++nt) {
      short8 bv = *(const short8*)(VT + (nt * 16 + fl) * 72 + kc * 32 + q * 8);
      accY[nt] = __builtin_amdgcn_mfma_f32_16x16x32_bf16(ap, bv, accY[nt], 0, 0, 0);
    }
  }
  // fused groupnorm epilogue: row t's 32 channels = {accY[0][rr] (i=fl),
  // accY[1][rr] (i=16+fl)} across the 16-lane fl group.
  float lw0 = lnw[h * HS_ + fl],      lb0 = lnb[h * HS_ + fl];
  float lw1 = lnw[h * HS_ + 16 + fl], lb1 = lnb[h * HS_ + 16 + fl];
  #pragma unroll
  for (int rr = 0; rr < 4; ++rr) {
    int t = wave * 16 + q * 4 + rr;
    float a0 = accY[0][rr], a1 = accY[1][rr];
    float mu = a0 + a1;
    mu += __shfl_xor(mu, 1); mu += __shfl_xor(mu, 2);
    mu += __shfl_xor(mu, 4); mu += __shfl_xor(mu, 8);
    mu *= (1.f / 32.f);
    float d0 = a0 - mu, d1 = a1 - mu;
    float ss = d0 * d0 + d1 * d1;
    ss += __shfl_xor(ss, 1); ss += __shfl_xor(ss, 2);
    ss += __shfl_xor(ss, 4); ss += __shfl_xor(ss, 8);
    float rs = rsqrtf(ss * (1.f / 32.f) + 1e-5f);
    size_t gi = gbase + (size_t)t * C_;
    float g0 = b2f(gg[gi + fl]);
    float g1 = b2f(gg[gi + 16 + fl]);
    z[gi + fl]      = f2b((d0 * rs * lw0 + lb0) * g0);
    z[gi + 16 + fl] = f2b((d1 * rs * lw1 + lb1) * g1);
  }
}

// ---------------------------------------------------------------------------
extern "C" void kernel_launch(void* const* d_in, const int* in_sizes, int n_in,
                              void* d_out, int out_size, void* d_ws, size_t ws_size,
                              hipStream_t stream) {
  (void)in_sizes; (void)n_in; (void)out_size; (void)ws_size;
  const float* x      = (const float*)d_in[0];
  const float* tmx    = (const float*)d_in[1];
  const float* tmw    = (const float*)d_in[2];
  const float* tmk    = (const float*)d_in[3];
  const float* tmv    = (const float*)d_in[4];
  const float* tmr    = (const float*)d_in[5];
  const float* tmg    = (const float*)d_in[6];
  const float* w1     = (const float*)d_in[7];
  const float* w2     = (const float*)d_in[8];
  const float* tdecay = (const float*)d_in[9];
  const float* wd1    = (const float*)d_in[10];
  const float* wd2    = (const float*)d_in[11];
  const float* faaaa  = (const float*)d_in[12];
  const float* Wr     = (const float*)d_in[13];
  const float* Wk     = (const float*)d_in[14];
  const float* Wv     = (const float*)d_in[15];
  const float* Wg     = (const float*)d_in[16];
  const float* Wo     = (const float*)d_in[17];
  const float* lnw    = (const float*)d_in[18];
  const float* lnb    = (const float*)d_in[19];
  float* out = (float*)d_out;

  // workspace layout — 6 x 16MB slots + st + weights; peak ~118 MB
  char* w8 = (char*)d_ws;
  const size_t MB = 1024ull * 1024ull;
  bf16* S0 = (bf16*)(w8 +  0 * MB);  // xxx -> xw -> ee
  bf16* S1 = (bf16*)(w8 + 16 * MB);  // xk -> vb
  bf16* S2 = (bf16*)(w8 + 32 * MB);  // xv -> gb
  bf16* S3 = (bf16*)(w8 + 48 * MB);  // xr -> kb
  bf16* S4 = (bf16*)(w8 + 64 * MB);  // xg -> z
  bf16* S5 = (bf16*)(w8 + 80 * MB);  // mix5p+h1 -> rb
  float* st = (float*)(w8 + 96 * MB);            // 16.5 MB
  char* wreg = w8 + 112 * MB + 512 * 1024;       // weights at 112.5 MB
  bf16* Wrb  = (bf16*)(wreg);
  bf16* Wkb  = Wrb + 2 * WSZ_;
  bf16* Wvb  = Wkb + 2 * WSZ_;
  bf16* Wgb  = Wvb + 2 * WSZ_;
  bf16* Wob  = Wgb + 2 * WSZ_;
  bf16* w1p  = Wob + 2 * WSZ_;                   // [192][512]
  bf16* wd1p = w1p + 192 * 512;                  // [64][512]
  bf16* w2p  = wd1p + 64 * 512;                  // [512][192]
  bf16* mix5p = S5;                              // [16384][192], 6 MB
  bf16* h1    = S5 + (size_t)BT_ * 192;          // [16384][64],  2 MB

  // 1. fused prep: xxx (S0) + weight splits + w1/wd1/w2 transpose
  prep_combo_kernel<<<PREP_N_, 256, 0, stream>>>(
      x, tmx, Wr, Wk, Wv, Wg, Wo, w1, wd1, w2,
      S0, Wrb, Wkb, Wvb, Wgb, Wob, w1p, wd1p, w2p);
  // 2. mix5p = tanh(xxx @ w1p^T)
  mfma_gemm_kernel<64, 3, 0><<<dim3(128, 3), 256, 0, stream>>>(S0, w1p, mix5p, 192);
  // 3. all five mixed activations in one MFMA pass (xxx dead -> xw over S0)
  mix_mfma_kernel<<<dim3(BT_ / 64, 8), 256, 0, stream>>>(
      mix5p, w2p, x, tmw, tmk, tmv, tmr, tmg, S0, S1, S2, S3, S4);
  // 4. h1 = tanh(xw @ wd1^T);  5. ee = exp(td + h1 @ wd2)  (ee over xw slot)
  mfma_gemm_kernel<64, 3, 0><<<dim3(128, 1), 256, 0, stream>>>(S0, wd1p, h1, 64);
  decay_kernel<<<BT_ / 8, 512, 0, stream>>>(h1, wd2, tdecay, S0);
  // 6-9. projections (split weights)
  dim3 gg(128, 4);
  mfma_gemm_kernel<128, 0, 1><<<gg, 256, 0, stream>>>(S3, Wrb, S5, C_);  // xr->rb(S5)
  mfma_gemm_kernel<128, 0, 1><<<gg, 256, 0, stream>>>(S1, Wkb, S3, C_);  // xk->kb(S3)
  mfma_gemm_kernel<128, 0, 1><<<gg, 256, 0, stream>>>(S2, Wvb, S1, C_);  // xv->vb(S1)
  mfma_gemm_kernel<128, 1, 1><<<gg, 256, 0, stream>>>(S4, Wgb, S2, C_);  // xg->gb(S2), silu
  // 10-12. chunk-parallel WKV6 scan (4-wave MFMA form, gnorm fused in final)
  wkv_partial_mfma<<<B_ * H_ * NC_, 256, 0, stream>>>(S3, S1, S0, st);
  wkv_stitch_kernel<<<B_ * H_, 64, 0, stream>>>(st);
  wkv_final_mfma<<<B_ * H_ * NC_, 256, 0, stream>>>(S5, S3, S1, S0, faaaa, st,
                                                    S2, lnw, lnb, S4);
  // 13. output projection (fp32) reads fused-gnorm z (S4)
  mfma_gemm_kernel<128, 2, 1><<<gg, 256, 0, stream>>>(S4, Wob, out, C_);
}

// Round 3
// 431.226 us; speedup vs baseline: 1.2893x; 1.0359x over previous
//
#include <hip/hip_runtime.h>
#include <hip/hip_bf16.h>

#define B_ 8
#define T_ 2048
#define C_ 512
#define H_ 16
#define HS_ 32
#define BT_ (B_*T_)   // 16384 tokens
#define CL_ 64        // scan chunk length
#define NC_ (T_/CL_)  // 32 chunks
#define STF_ 1056     // floats per (bh,chunk) state: 1024 S + 32 P
#define WSZ_ 262144   // elements per 512x512 weight (2^18)

typedef __hip_bfloat16 bf16;
typedef __attribute__((ext_vector_type(8))) short short8;
typedef __attribute__((ext_vector_type(4))) float f32x4;

__device__ __forceinline__ float b2f(bf16 v) { return __bfloat162float(v); }
__device__ __forceinline__ bf16 f2b(float v) { return __float2bfloat16(v); }

// async global->LDS 16B direct copy (m97 structure). LDS dst must be
// wave-uniform base + lane*16 — all call sites use &LDS[tid(+k)] which is.
__device__ __forceinline__ void gl2lds(const void* g, void* l) {
  __builtin_amdgcn_global_load_lds(
      (const __attribute__((address_space(1))) void*)g,
      (__attribute__((address_space(3))) void*)l, 16, 0, 0);
}

// ---------------------------------------------------------------------------
// prep_combo: one launch does (a) xxx = x + (xshift-x)*maa_x, (b) hi/lo bf16
// split of the five 512x512 weights, (c) transpose+pad w1 -> [192][512] and
// wd1 -> [64][512], (d) transpose+pad w2 -> [512][192] bf16 for mix_mfma.
// ---------------------------------------------------------------------------
__global__ __launch_bounds__(256) void prep_combo_kernel(
    const float* __restrict__ x, const float* __restrict__ tmx,
    const float* __restrict__ Wr, const float* __restrict__ Wk,
    const float* __restrict__ Wv, const float* __restrict__ Wg,
    const float* __restrict__ Wo, const float* __restrict__ w1,
    const float* __restrict__ wd1, const float* __restrict__ w2,
    bf16* __restrict__ xxx, bf16* __restrict__ Wrb, bf16* __restrict__ Wkb,
    bf16* __restrict__ Wvb, bf16* __restrict__ Wgb, bf16* __restrict__ Wob,
    bf16* __restrict__ w1p, bf16* __restrict__ wd1p, bf16* __restrict__ w2p) {
  int idx = blockIdx.x * 256 + threadIdx.x;
  if (idx < BT_ * C_) {                       // token-shift mix input
    int c = idx & (C_ - 1);
    int t = (idx >> 9) & (T_ - 1);
    float xc = x[idx];
    float xp = (t == 0) ? 0.f : x[idx - C_];
    xxx[idx] = f2b(xc + (xp - xc) * tmx[c]);
    return;
  }
  idx -= BT_ * C_;
  if (idx < 5 * WSZ_) {                       // weight hi/lo split
    int w = idx >> 18;
    int i = idx & (WSZ_ - 1);
    const float* src = (w == 0) ? Wr : (w == 1) ? Wk : (w == 2) ? Wv
                     : (w == 3) ? Wg : Wo;
    bf16* dst = (w == 0) ? Wrb : (w == 1) ? Wkb : (w == 2) ? Wvb
              : (w == 3) ? Wgb : Wob;
    float s = src[i];
    bf16 hi = f2b(s);
    dst[i] = hi;
    dst[WSZ_ + i] = f2b(s - b2f(hi));
    return;
  }
  idx -= 5 * WSZ_;
  if (idx < 192 * 512) {                      // w1^T padded to 192 rows
    int n = idx >> 9, k = idx & (C_ - 1);
    w1p[idx] = f2b(n < 160 ? w1[k * 160 + n] : 0.f);
    return;
  }
  idx -= 192 * 512;
  if (idx < 64 * 512) {                       // wd1^T [64][512]
    int n = idx >> 9, k = idx & (C_ - 1);
    wd1p[idx] = f2b(wd1[k * 64 + n]);
    return;
  }
  idx -= 64 * 512;
  {                                           // w2^T padded [512][192]
    int c = idx / 192, n = idx - c * 192;     // n = f*32+d
    w2p[idx] = f2b(n < 160 ? w2[(size_t)n * C_ + c] : 0.f);
  }
}
#define PREP_N_ ((BT_*C_ + 5*WSZ_ + 192*512 + 64*512 + 512*192) / 256) // 38784

// ---------------------------------------------------------------------------
// MFMA GEMM: O = act(A @ Bw^T). BM=128, BK=32, 256 thr.
// Staging via global_load_lds (async direct-to-LDS, 16B): per K-step
// {barrier; issue loads; barrier(drains vmcnt); ds_read frags; MFMA}.
// MODE: 0 bf16; 1 bf16+silu; 2 fp32; 3 bf16+tanh.  N = output stride.
// ---------------------------------------------------------------------------
template<int BN, int MODE, int SPLIT>
__global__ __launch_bounds__(256) void mfma_gemm_kernel(
    const bf16* __restrict__ A, const bf16* __restrict__ Bw,
    void* __restrict__ O, int N) {
  constexpr int BM = 128, BK = 32;
  constexpr int AE = BM * BK / 8;
  constexpr int BE = BN * BK / 8;
  __shared__ short8 Asm[AE];
  __shared__ short8 Bsm[BE];
  __shared__ short8 Lsm[SPLIT ? BE : 1];
  const int tid = threadIdx.x;
  const int lane = tid & 63;
  const int wave = tid >> 6;
  const int m0 = blockIdx.x * BM;
  const int n0 = blockIdx.y * BN;
  const int wm = (BN == 128) ? (wave >> 1) * 64 : wave * 32;
  const int wn = (BN == 128) ? (wave & 1) * 64 : 0;
  constexpr int MT = (BN == 128) ? 4 : 2;
  constexpr int NT = 4;
  f32x4 acc[MT][NT] = {};
  const int e0 = tid, e1 = tid + 256;
  const int r0 = ((e0 >> 6) << 4) | (e0 & 15), q0 = (e0 >> 4) & 3;
  const int r1 = ((e1 >> 6) << 4) | (e1 & 15), q1 = (e1 >> 4) & 3;
  const unsigned short* Au = (const unsigned short*)A;
  const unsigned short* Bu = (const unsigned short*)Bw;
  const unsigned short* Lu = Bu + (SPLIT ? WSZ_ : 0);
  for (int k0 = 0; k0 < C_; k0 += BK) {
    __syncthreads();   // all ds_reads of previous iteration complete
    gl2lds(&Au[(size_t)(m0 + r0) * C_ + k0 + q0 * 8], &Asm[e0]);
    gl2lds(&Au[(size_t)(m0 + r1) * C_ + k0 + q1 * 8], &Asm[e1]);
    gl2lds(&Bu[(size_t)(n0 + r0) * C_ + k0 + q0 * 8], &Bsm[e0]);
    if constexpr (BN == 128)
      gl2lds(&Bu[(size_t)(n0 + r1) * C_ + k0 + q1 * 8], &Bsm[e1]);
    if constexpr (SPLIT) {
      gl2lds(&Lu[(size_t)(n0 + r0) * C_ + k0 + q0 * 8], &Lsm[e0]);
      if constexpr (BN == 128)
        gl2lds(&Lu[(size_t)(n0 + r1) * C_ + k0 + q1 * 8], &Lsm[e1]);
    }
    __syncthreads();   // implicit vmcnt(0) drain -> LDS tile ready
    short8 af[MT], bh[NT];
    #pragma unroll
    for (int mt = 0; mt < MT; ++mt) af[mt] = Asm[((wm >> 4) + mt) * 64 + lane];
    #pragma unroll
    for (int nt = 0; nt < NT; ++nt) bh[nt] = Bsm[((wn >> 4) + nt) * 64 + lane];
    #pragma unroll
    for (int mt = 0; mt < MT; ++mt)
      #pragma unroll
      for (int nt = 0; nt < NT; ++nt)
        acc[mt][nt] = __builtin_amdgcn_mfma_f32_16x16x32_bf16(
            af[mt], bh[nt], acc[mt][nt], 0, 0, 0);
    if constexpr (SPLIT) {
      short8 bl[NT];
      #pragma unroll
      for (int nt = 0; nt < NT; ++nt) bl[nt] = Lsm[((wn >> 4) + nt) * 64 + lane];
      #pragma unroll
      for (int mt = 0; mt < MT; ++mt)
        #pragma unroll
        for (int nt = 0; nt < NT; ++nt)
          acc[mt][nt] = __builtin_amdgcn_mfma_f32_16x16x32_bf16(
              af[mt], bl[nt], acc[mt][nt], 0, 0, 0);
    }
  }
  const int col = lane & 15, qr = lane >> 4;
  #pragma unroll
  for (int mt = 0; mt < MT; ++mt) {
    int mrow = m0 + wm + mt * 16 + qr * 4;
    #pragma unroll
    for (int nt = 0; nt < NT; ++nt) {
      int nc = n0 + wn + nt * 16 + col;
      #pragma unroll
      for (int r = 0; r < 4; ++r) {
        float v = acc[mt][nt][r];
        if (MODE == 1) v = v / (1.f + __expf(-v));
        if (MODE == 3) v = tanhf(v);
        size_t oi = (size_t)(mrow + r) * N + nc;
        if (MODE == 2) ((float*)O)[oi] = v;
        else           ((bf16*)O)[oi] = f2b(v);
      }
    }
  }
}

// ---------------------------------------------------------------------------
// mix_mfma (verified round 0): five K=32 GEMMs via MFMA fused with the
// elementwise epilogue x_f = x + (xshift-x)*(tm_f + m_f).
// ---------------------------------------------------------------------------
__global__ __launch_bounds__(256) void mix_mfma_kernel(
    const bf16* __restrict__ mix5, const bf16* __restrict__ w2p,
    const float* __restrict__ x,
    const float* __restrict__ tmw, const float* __restrict__ tmk,
    const float* __restrict__ tmv, const float* __restrict__ tmr,
    const float* __restrict__ tmg,
    bf16* __restrict__ xw, bf16* __restrict__ xk, bf16* __restrict__ xv,
    bf16* __restrict__ xr, bf16* __restrict__ xg) {
  constexpr int LDP = 200;
  __shared__ __align__(16) unsigned short Asm[64 * LDP];
  __shared__ __align__(16) unsigned short Bsm[64 * LDP];
  const int tid = threadIdx.x;
  const int row0 = blockIdx.x * 64;
  const int col0 = blockIdx.y * 64;
  const unsigned short* Au = (const unsigned short*)mix5;
  const unsigned short* Bu = (const unsigned short*)w2p;
  #pragma unroll
  for (int e0 = 0; e0 < 64 * 20; e0 += 256) {
    int e = e0 + tid;
    int rr = e / 20, p = e - rr * 20;
    *(short8*)&Asm[rr * LDP + p * 8] =
        *(const short8*)&Au[(size_t)(row0 + rr) * 192 + p * 8];
    *(short8*)&Bsm[rr * LDP + p * 8] =
        *(const short8*)&Bu[(size_t)(col0 + rr) * 192 + p * 8];
  }
  __syncthreads();
  const int lane = tid & 63, wave = tid >> 6;
  const int fl = lane & 15, q = lane >> 4;
  short8 af[5];
  #pragma unroll
  for (int f = 0; f < 5; ++f)
    af[f] = *(const short8*)&Asm[(wave * 16 + fl) * LDP + f * 32 + q * 8];
  f32x4 acc[4][5] = {};
  #pragma unroll
  for (int nt = 0; nt < 4; ++nt)
    #pragma unroll
    for (int f = 0; f < 5; ++f) {
      short8 bfr = *(const short8*)&Bsm[(nt * 16 + fl) * LDP + f * 32 + q * 8];
      acc[nt][f] = __builtin_amdgcn_mfma_f32_16x16x32_bf16(
          af[f], bfr, acc[nt][f], 0, 0, 0);
    }
  #pragma unroll
  for (int nt = 0; nt < 4; ++nt) {
    int cc = col0 + nt * 16 + fl;
    float vw = tmw[cc], vk = tmk[cc], vv = tmv[cc], vr = tmr[cc],
          vg = tmg[cc];
    #pragma unroll
    for (int r = 0; r < 4; ++r) {
      int rr = row0 + wave * 16 + q * 4 + r;
      size_t idx = (size_t)rr * C_ + cc;
      float xc = x[idx];
      float xx = (((rr & (T_ - 1)) == 0) ? 0.f : x[idx - C_]) - xc;
      xw[idx] = f2b(xc + xx * (vw + acc[nt][0][r]));
      xk[idx] = f2b(xc + xx * (vk + acc[nt][1][r]));
      xv[idx] = f2b(xc + xx * (vv + acc[nt][2][r]));
      xr[idx] = f2b(xc + xx * (vr + acc[nt][3][r]));
      xg[idx] = f2b(xc + xx * (vg + acc[nt][4][r]));
    }
  }
}

// ---------------------------------------------------------------------------
// decay (unchanged, verified): w = td + h1 @ Wd2 (K=64); ee = exp(w) bf16.
// ---------------------------------------------------------------------------
__global__ __launch_bounds__(512) void decay_kernel(
    const bf16* __restrict__ h1, const float* __restrict__ wd2,
    const float* __restrict__ tdecay, bf16* __restrict__ ee) {
  __shared__ float Hs[8][64];
  int row0 = blockIdx.x * 8;
  {
    int e = threadIdx.x;
    Hs[e >> 6][e & 63] = b2f(h1[(size_t)(row0 + (e >> 6)) * 64 + (e & 63)]);
  }
  __syncthreads();
  int c = threadIdx.x;
  float acc[8] = {0.f,0.f,0.f,0.f,0.f,0.f,0.f,0.f};
  for (int j = 0; j < 64; ++j) {
    float wv = wd2[j * C_ + c];
    #pragma unroll
    for (int r = 0; r < 8; ++r) acc[r] += Hs[r][j] * wv;
  }
  float td = tdecay[c];
  #pragma unroll
  for (int r = 0; r < 8; ++r)
    ee[(size_t)(row0 + r) * C_ + c] = f2b(expf(td + acc[r]));
}

// ---------------------------------------------------------------------------
// WKV6 chunked scan — 4-wave form (verified round 1).
// ---------------------------------------------------------------------------
__global__ __launch_bounds__(256) void wkv_partial_mfma(
    const bf16* __restrict__ k, const bf16* __restrict__ v,
    const bf16* __restrict__ ee, float* __restrict__ st) {
  __shared__ __align__(16) char smem[17536];
  float* Lm  = (float*)smem;              // [65][32] floats, 8320 B
  bf16*  K2T = (bf16*)(smem + 8320);      // [32][72]
  bf16*  VT  = (bf16*)(smem + 12928);     // [32][72]
  bf16*  Eb  = K2T;                       // [64][32] scratch (dead pre-stage)
  int g = blockIdx.x;
  int bh = g >> 5, c = g & (NC_ - 1);
  int b = bh >> 4, h = bh & 15;
  const int tid = threadIdx.x;
  const int lane = tid & 63, wave = tid >> 6;
  const int ch = lane & 31, th = lane >> 5;
  size_t gbase = (size_t)b * T_ * C_ + (size_t)(c * CL_) * C_ + h * HS_;
  #pragma unroll
  for (int it = 0; it < 8; ++it) {
    int e = it * 256 + tid;
    Eb[e] = ee[gbase + (size_t)(e >> 5) * C_ + (e & 31)];
  }
  float kv[8]; bf16 vv[8];
  #pragma unroll
  for (int it = 0; it < 8; ++it) {
    int t = wave * 16 + it * 2 + th;
    size_t gi = gbase + (size_t)t * C_ + ch;
    kv[it] = b2f(k[gi]);
    vv[it] = v[gi];
  }
  __syncthreads();
  if (tid < 32) {
    float L = 0.f;
    for (int t = 0; t < CL_; ++t) {
      Lm[t * 32 + tid] = L;
      L -= b2f(Eb[t * 32 + tid]);
    }
    Lm[64 * 32 + tid] = L;
  }
  __syncthreads();
  float Ltot = Lm[64 * 32 + ch];
  #pragma unroll
  for (int it = 0; it < 8; ++it) {
    int t = wave * 16 + it * 2 + th;
    float Lt1 = Lm[(t + 1) * 32 + ch];
    K2T[ch * 72 + t] = f2b(kv[it] * __expf(Ltot - Lt1));
    VT [ch * 72 + t] = vv[it];
  }
  __syncthreads();
  const int fl = lane & 15, q = lane >> 4;
  const int mt = wave >> 1, nt = wave & 1;
  f32x4 accS = {};
  #pragma unroll
  for (int kc = 0; kc < 2; ++kc) {
    short8 av = *(const short8*)(VT + (mt * 16 + fl) * 72 + kc * 32 + q * 8);
    short8 bk = *(const short8*)(K2T + (nt * 16 + fl) * 72 + kc * 32 + q * 8);
    accS = __builtin_amdgcn_mfma_f32_16x16x32_bf16(av, bk, accS, 0, 0, 0);
  }
  size_t sbase = (size_t)g * STF_;
  #pragma unroll
  for (int r = 0; r < 4; ++r)
    st[sbase + (size_t)(mt * 16 + q * 4 + r) * 32 + nt * 16 + fl] = accS[r];
  if (tid < 32) st[sbase + 1024 + tid] = __expf(Lm[64 * 32 + tid]);
}

// ---------------------------------------------------------------------------
// stitch: serial chunk recurrence R = P*R + Sc per (bh). The incoming state
// for chunk c (= R before update) is emitted as bf16 hi/lo in MFMA B-fragment
// order into the DEAD S-region of slot c-1 (its fp32 S was consumed at the
// previous iteration; wave-wide s_waitcnt on those loads precedes the store
// instruction, so no hazard). Chunk 0's incoming state is zero (final skips).
// ---------------------------------------------------------------------------
__global__ __launch_bounds__(64) void wkv_stitch_kernel(float* __restrict__ st) {
  int bh = blockIdx.x;
  int lane = threadIdx.x;
  int i = lane & 31, half = lane >> 5;
  float R[16];
  #pragma unroll
  for (int jj = 0; jj < 16; ++jj) R[jj] = 0.f;
  for (int c = 0; c < NC_; ++c) {
    size_t s = ((size_t)bh * NC_ + c) * STF_;
    const float* sp = st + s + i * 32 + (half << 4);
    float Sc[16];
    float4* sc4 = reinterpret_cast<float4*>(Sc);
    const float4* sp4 = reinterpret_cast<const float4*>(sp);
    #pragma unroll
    for (int q = 0; q < 4; ++q) sc4[q] = sp4[q];
    float Pj[16];
    #pragma unroll
    for (int jj = 0; jj < 16; ++jj) Pj[jj] = st[s + 1024 + (half << 4) + jj];
    if (c > 0) {
      __align__(16) bf16 hi16[16], lo16[16];
      #pragma unroll
      for (int jj = 0; jj < 16; ++jj) {
        bf16 hb = f2b(R[jj]);
        hi16[jj] = hb;
        lo16[jj] = f2b(R[jj] - b2f(hb));
      }
      bf16* sb = (bf16*)(st + s - STF_);
      short8* dh = (short8*)(sb + i * 32 + (half << 4));
      short8* dl = (short8*)(sb + 1024 + i * 32 + (half << 4));
      const short8* ph = (const short8*)hi16;
      const short8* pl = (const short8*)lo16;
      dh[0] = ph[0]; dh[1] = ph[1];
      dl[0] = pl[0]; dl[1] = pl[1];
    }
    #pragma unroll
    for (int jj = 0; jj < 16; ++jj) R[jj] = fmaf(Pj[jj], R[jj], Sc[jj]);
  }
}

// ---------------------------------------------------------------------------
// wkv_final: 4-wave + fused groupnorm. S fragments loaded DIRECTLY from the
// stitched bf16 hi/lo state (slot g-1; zero for chunk 0) — no Sh/Sl LDS, no
// fp32->bf16 convert loop. LDS 24320B -> 6 blocks/CU.
// ---------------------------------------------------------------------------
__global__ __launch_bounds__(256) void wkv_final_mfma(
    const bf16* __restrict__ r, const bf16* __restrict__ k,
    const bf16* __restrict__ v, const bf16* __restrict__ ee,
    const float* __restrict__ faaaa, const float* __restrict__ st,
    const bf16* __restrict__ gg, const float* __restrict__ lnw,
    const float* __restrict__ lnb, bf16* __restrict__ z) {
  __shared__ __align__(16) char smem[24320];
  float* Lm = (float*)smem;               // [65][32] — aliased by Pm later
  bf16*  Pm = (bf16*)smem;                // [64][72]
  bf16*  RA = (bf16*)(smem + 9216);       // [64][40]
  bf16*  Kd = (bf16*)(smem + 14336);      // [64][40]
  bf16*  VT = (bf16*)(smem + 19456);      // [32][72]
  bf16*  Eb = VT;                         // [64][32] scratch (dead pre-stage)
  float* bon = (float*)(smem + 24064);    // [64]
  int g = blockIdx.x;
  int bh = g >> 5, c = g & (NC_ - 1);
  int b = bh >> 4, h = bh & 15;
  const int tid = threadIdx.x;
  const int lane = tid & 63, wave = tid >> 6;
  const int ch = lane & 31, th = lane >> 5;
  const int fl = lane & 15, q = lane >> 4;
  size_t gbase = (size_t)b * T_ * C_ + (size_t)(c * CL_) * C_ + h * HS_;
  size_t sbase = (size_t)g * STF_;
  // ee tile -> LDS scratch (coalesced); S fragments from global; r/k/v regs
  #pragma unroll
  for (int it = 0; it < 8; ++it) {
    int e = it * 256 + tid;
    Eb[e] = ee[gbase + (size_t)(e >> 5) * C_ + (e & 31)];
  }
  short8 sh[2] = {}, sl[2] = {};
  if (c != 0) {
    const unsigned short* sb = (const unsigned short*)(st + sbase - STF_);
    #pragma unroll
    for (int nt = 0; nt < 2; ++nt) {
      sh[nt] = *(const short8*)&sb[(nt * 16 + fl) * 32 + q * 8];
      sl[nt] = *(const short8*)&sb[1024 + (nt * 16 + fl) * 32 + q * 8];
    }
  }
  float rv[8], kv[8]; bf16 vv[8];
  #pragma unroll
  for (int it = 0; it < 8; ++it) {
    int t = wave * 16 + it * 2 + th;
    size_t gi = gbase + (size_t)t * C_ + ch;
    rv[it] = b2f(r[gi]); kv[it] = b2f(k[gi]); vv[it] = v[gi];
  }
  __syncthreads();
  // serial prefix scan on LDS latency only
  if (tid < 32) {
    float L = 0.f;
    for (int t = 0; t < CL_; ++t) {
      Lm[t * 32 + tid] = L;
      L -= b2f(Eb[t * 32 + tid]);
    }
    Lm[64 * 32 + tid] = L;
  }
  __syncthreads();
  float u_j = faaaa[h * HS_ + ch];
  #pragma unroll
  for (int it = 0; it < 8; ++it) {
    int t = wave * 16 + it * 2 + th;
    float Lt  = Lm[t * 32 + ch];
    float Lt1 = Lm[(t + 1) * 32 + ch];
    RA[t * 40 + ch] = f2b(rv[it] * __expf(Lt));
    Kd[t * 40 + ch] = f2b(kv[it] * __expf(-Lt1));
    VT[ch * 72 + t] = vv[it];
    float pb = rv[it] * u_j * kv[it];
    pb += __shfl_xor(pb, 1); pb += __shfl_xor(pb, 2);
    pb += __shfl_xor(pb, 4); pb += __shfl_xor(pb, 8);
    pb += __shfl_xor(pb, 16);
    if (ch == 0) bon[t] = pb;
  }
  __syncthreads();
  short8 afr = *(const short8*)(RA + (wave * 16 + fl) * 40 + q * 8);
  f32x4 accY[2] = {};
  #pragma unroll
  for (int nt = 0; nt < 2; ++nt) {
    accY[nt] = __builtin_amdgcn_mfma_f32_16x16x32_bf16(afr, sh[nt], accY[nt], 0, 0, 0);
    accY[nt] = __builtin_amdgcn_mfma_f32_16x16x32_bf16(afr, sl[nt], accY[nt], 0, 0, 0);
  }
  f32x4 accP[4] = {};
  #pragma unroll
  for (int s4 = 0; s4 < 4; ++s4) {
    short8 bk = *(const short8*)(Kd + (s4 * 16 + fl) * 40 + q * 8);
    accP[s4] = __builtin_amdgcn_mfma_f32_16x16x32_bf16(afr, bk, accP[s4], 0, 0, 0);
  }
  // write own Pm band (Lm dead: last read was pre-MFMA barrier)
  #pragma unroll
  for (int s4 = 0; s4 < 4; ++s4)
    #pragma unroll
    for (int rr = 0; rr < 4; ++rr) {
      int t = wave * 16 + q * 4 + rr;
      int s = s4 * 16 + fl;
      float pv = accP[s4][rr];
      float bv = bon[t];
      pv = (s < t) ? pv : ((s == t) ? bv : 0.f);
      Pm[t * 72 + s] = f2b(pv);
    }
  __syncthreads();
  #pragma unroll
  for (int kc = 0; kc < 2; ++kc) {
    short8 ap = *(const short8*)(Pm + (wave * 16 + fl) * 72 + kc * 32 + q * 8);
    #pragma unroll
    for (int nt = 0; nt < 2; ++nt) {
      short8 bv = *(const short8*)(VT + (nt * 16 + fl) * 72 + kc * 32 + q * 8);
      accY[nt] = __builtin_amdgcn_mfma_f32_16x16x32_bf16(ap, bv, accY[nt], 0, 0, 0);
    }
  }
  // fused groupnorm epilogue
  float lw0 = lnw[h * HS_ + fl],      lb0 = lnb[h * HS_ + fl];
  float lw1 = lnw[h * HS_ + 16 + fl], lb1 = lnb[h * HS_ + 16 + fl];
  #pragma unroll
  for (int rr = 0; rr < 4; ++rr) {
    int t = wave * 16 + q * 4 + rr;
    float a0 = accY[0][rr], a1 = accY[1][rr];
    float mu = a0 + a1;
    mu += __shfl_xor(mu, 1); mu += __shfl_xor(mu, 2);
    mu += __shfl_xor(mu, 4); mu += __shfl_xor(mu, 8);
    mu *= (1.f / 32.f);
    float d0 = a0 - mu, d1 = a1 - mu;
    float ss = d0 * d0 + d1 * d1;
    ss += __shfl_xor(ss, 1); ss += __shfl_xor(ss, 2);
    ss += __shfl_xor(ss, 4); ss += __shfl_xor(ss, 8);
    float rs = rsqrtf(ss * (1.f / 32.f) + 1e-5f);
    size_t gi = gbase + (size_t)t * C_;
    float g0 = b2f(gg[gi + fl]);
    float g1 = b2f(gg[gi + 16 + fl]);
    z[gi + fl]      = f2b((d0 * rs * lw0 + lb0) * g0);
    z[gi + 16 + fl] = f2b((d1 * rs * lw1 + lb1) * g1);
  }
}

// ---------------------------------------------------------------------------
extern "C" void kernel_launch(void* const* d_in, const int* in_sizes, int n_in,
                              void* d_out, int out_size, void* d_ws, size_t ws_size,
                              hipStream_t stream) {
  (void)in_sizes; (void)n_in; (void)out_size; (void)ws_size;
  const float* x      = (const float*)d_in[0];
  const float* tmx    = (const float*)d_in[1];
  const float* tmw    = (const float*)d_in[2];
  const float* tmk    = (const float*)d_in[3];
  const float* tmv    = (const float*)d_in[4];
  const float* tmr    = (const float*)d_in[5];
  const float* tmg    = (const float*)d_in[6];
  const float* w1     = (const float*)d_in[7];
  const float* w2     = (const float*)d_in[8];
  const float* tdecay = (const float*)d_in[9];
  const float* wd1    = (const float*)d_in[10];
  const float* wd2    = (const float*)d_in[11];
  const float* faaaa  = (const float*)d_in[12];
  const float* Wr     = (const float*)d_in[13];
  const float* Wk     = (const float*)d_in[14];
  const float* Wv     = (const float*)d_in[15];
  const float* Wg     = (const float*)d_in[16];
  const float* Wo     = (const float*)d_in[17];
  const float* lnw    = (const float*)d_in[18];
  const float* lnb    = (const float*)d_in[19];
  float* out = (float*)d_out;

  // workspace layout — 6 x 16MB slots + st + weights; peak ~118 MB
  char* w8 = (char*)d_ws;
  const size_t MB = 1024ull * 1024ull;
  bf16* S0 = (bf16*)(w8 +  0 * MB);  // xxx -> xw -> ee
  bf16* S1 = (bf16*)(w8 + 16 * MB);  // xk -> vb
  bf16* S2 = (bf16*)(w8 + 32 * MB);  // xv -> gb
  bf16* S3 = (bf16*)(w8 + 48 * MB);  // xr -> kb
  bf16* S4 = (bf16*)(w8 + 64 * MB);  // xg -> z
  bf16* S5 = (bf16*)(w8 + 80 * MB);  // mix5p+h1 -> rb
  float* st = (float*)(w8 + 96 * MB);            // 16.5 MB
  char* wreg = w8 + 112 * MB + 512 * 1024;       // weights at 112.5 MB
  bf16* Wrb  = (bf16*)(wreg);
  bf16* Wkb  = Wrb + 2 * WSZ_;
  bf16* Wvb  = Wkb + 2 * WSZ_;
  bf16* Wgb  = Wvb + 2 * WSZ_;
  bf16* Wob  = Wgb + 2 * WSZ_;
  bf16* w1p  = Wob + 2 * WSZ_;                   // [192][512]
  bf16* wd1p = w1p + 192 * 512;                  // [64][512]
  bf16* w2p  = wd1p + 64 * 512;                  // [512][192]
  bf16* mix5p = S5;                              // [16384][192], 6 MB
  bf16* h1    = S5 + (size_t)BT_ * 192;          // [16384][64],  2 MB

  // 1. fused prep: xxx (S0) + weight splits + w1/wd1/w2 transpose
  prep_combo_kernel<<<PREP_N_, 256, 0, stream>>>(
      x, tmx, Wr, Wk, Wv, Wg, Wo, w1, wd1, w2,
      S0, Wrb, Wkb, Wvb, Wgb, Wob, w1p, wd1p, w2p);
  // 2. mix5p = tanh(xxx @ w1p^T)
  mfma_gemm_kernel<64, 3, 0><<<dim3(128, 3), 256, 0, stream>>>(S0, w1p, mix5p, 192);
  // 3. all five mixed activations in one MFMA pass (xxx dead -> xw over S0)
  mix_mfma_kernel<<<dim3(BT_ / 64, 8), 256, 0, stream>>>(
      mix5p, w2p, x, tmw, tmk, tmv, tmr, tmg, S0, S1, S2, S3, S4);
  // 4. h1 = tanh(xw @ wd1^T);  5. ee = exp(td + h1 @ wd2)  (ee over xw slot)
  mfma_gemm_kernel<64, 3, 0><<<dim3(128, 1), 256, 0, stream>>>(S0, wd1p, h1, 64);
  decay_kernel<<<BT_ / 8, 512, 0, stream>>>(h1, wd2, tdecay, S0);
  // 6-9. projections (split weights)
  dim3 gg(128, 4);
  mfma_gemm_kernel<128, 0, 1><<<gg, 256, 0, stream>>>(S3, Wrb, S5, C_);  // xr->rb(S5)
  mfma_gemm_kernel<128, 0, 1><<<gg, 256, 0, stream>>>(S1, Wkb, S3, C_);  // xk->kb(S3)
  mfma_gemm_kernel<128, 0, 1><<<gg, 256, 0, stream>>>(S2, Wvb, S1, C_);  // xv->vb(S1)
  mfma_gemm_kernel<128, 1, 1><<<gg, 256, 0, stream>>>(S4, Wgb, S2, C_);  // xg->gb(S2), silu
  // 10-12. chunk-parallel WKV6 scan (4-wave MFMA form, gnorm fused in final)
  wkv_partial_mfma<<<B_ * H_ * NC_, 256, 0, stream>>>(S3, S1, S0, st);
  wkv_stitch_kernel<<<B_ * H_, 64, 0, stream>>>(st);
  wkv_final_mfma<<<B_ * H_ * NC_, 256, 0, stream>>>(S5, S3, S1, S0, faaaa, st,
                                                    S2, lnw, lnb, S4);
  // 13. output projection (fp32) reads fused-gnorm z (S4)
  mfma_gemm_kernel<128, 2, 1><<<gg, 256, 0, stream>>>(S4, Wob, out, C_);
}

// Round 4
// 416.566 us; speedup vs baseline: 1.3347x; 1.0352x over previous
//
#include <hip/hip_runtime.h>
#include <hip/hip_bf16.h>

#define B_ 8
#define T_ 2048
#define C_ 512
#define H_ 16
#define HS_ 32
#define BT_ (B_*T_)   // 16384 tokens
#define CL_ 64        // scan chunk length
#define NC_ (T_/CL_)  // 32 chunks
#define STF_ 1056     // floats per (bh,chunk) state: 1024 S + 32 P
#define WSZ_ 262144   // elements per 512x512 weight (2^18)

typedef __hip_bfloat16 bf16;
typedef __attribute__((ext_vector_type(8))) short short8;
typedef __attribute__((ext_vector_type(4))) short short4v;
typedef __attribute__((ext_vector_type(4))) float f32x4;

__device__ __forceinline__ float b2f(bf16 v) { return __bfloat162float(v); }
__device__ __forceinline__ bf16 f2b(float v) { return __float2bfloat16(v); }
// raw-bits helpers for vectorized bf16 handling
__device__ __forceinline__ float s2f(short s) {
  unsigned u = ((unsigned)(unsigned short)s) << 16;
  return __builtin_bit_cast(float, u);
}
__device__ __forceinline__ short f2s(float f) {
  bf16 b = f2b(f);
  return __builtin_bit_cast(short, b);
}

// async global->LDS 16B direct copy (m97 structure). LDS dst must be
// wave-uniform base + lane*16 — all call sites use &LDS[tid(+k)] which is.
__device__ __forceinline__ void gl2lds(const void* g, void* l) {
  __builtin_amdgcn_global_load_lds(
      (const __attribute__((address_space(1))) void*)g,
      (__attribute__((address_space(3))) void*)l, 16, 0, 0);
}

// ---------------------------------------------------------------------------
// prep_combo: one launch does (a) xxx = x + (xshift-x)*maa_x, (b) hi/lo bf16
// split of the five 512x512 weights, (c) transpose+pad w1 -> [192][512] and
// wd1 -> [64][512], (d) transpose+pad w2 -> [512][192] bf16 for mix_mfma.
// ---------------------------------------------------------------------------
__global__ __launch_bounds__(256) void prep_combo_kernel(
    const float* __restrict__ x, const float* __restrict__ tmx,
    const float* __restrict__ Wr, const float* __restrict__ Wk,
    const float* __restrict__ Wv, const float* __restrict__ Wg,
    const float* __restrict__ Wo, const float* __restrict__ w1,
    const float* __restrict__ wd1, const float* __restrict__ w2,
    bf16* __restrict__ xxx, bf16* __restrict__ Wrb, bf16* __restrict__ Wkb,
    bf16* __restrict__ Wvb, bf16* __restrict__ Wgb, bf16* __restrict__ Wob,
    bf16* __restrict__ w1p, bf16* __restrict__ wd1p, bf16* __restrict__ w2p) {
  int idx = blockIdx.x * 256 + threadIdx.x;
  if (idx < BT_ * C_) {                       // token-shift mix input
    int c = idx & (C_ - 1);
    int t = (idx >> 9) & (T_ - 1);
    float xc = x[idx];
    float xp = (t == 0) ? 0.f : x[idx - C_];
    xxx[idx] = f2b(xc + (xp - xc) * tmx[c]);
    return;
  }
  idx -= BT_ * C_;
  if (idx < 5 * WSZ_) {                       // weight hi/lo split
    int w = idx >> 18;
    int i = idx & (WSZ_ - 1);
    const float* src = (w == 0) ? Wr : (w == 1) ? Wk : (w == 2) ? Wv
                     : (w == 3) ? Wg : Wo;
    bf16* dst = (w == 0) ? Wrb : (w == 1) ? Wkb : (w == 2) ? Wvb
              : (w == 3) ? Wgb : Wob;
    float s = src[i];
    bf16 hi = f2b(s);
    dst[i] = hi;
    dst[WSZ_ + i] = f2b(s - b2f(hi));
    return;
  }
  idx -= 5 * WSZ_;
  if (idx < 192 * 512) {                      // w1^T padded to 192 rows
    int n = idx >> 9, k = idx & (C_ - 1);
    w1p[idx] = f2b(n < 160 ? w1[k * 160 + n] : 0.f);
    return;
  }
  idx -= 192 * 512;
  if (idx < 64 * 512) {                       // wd1^T [64][512]
    int n = idx >> 9, k = idx & (C_ - 1);
    wd1p[idx] = f2b(wd1[k * 64 + n]);
    return;
  }
  idx -= 64 * 512;
  {                                           // w2^T padded [512][192]
    int c = idx / 192, n = idx - c * 192;     // n = f*32+d
    w2p[idx] = f2b(n < 160 ? w2[(size_t)n * C_ + c] : 0.f);
  }
}
#define PREP_N_ ((BT_*C_ + 5*WSZ_ + 192*512 + 64*512 + 512*192) / 256) // 38784

// ---------------------------------------------------------------------------
// MFMA GEMM: O = act(A @ Bw^T). BM=128, BK=32, 256 thr.
// Staging via global_load_lds (verified round 2).
// MODE: 0 bf16; 1 bf16+silu; 2 fp32; 3 bf16+tanh.  N = output stride.
// ---------------------------------------------------------------------------
template<int BN, int MODE, int SPLIT>
__global__ __launch_bounds__(256) void mfma_gemm_kernel(
    const bf16* __restrict__ A, const bf16* __restrict__ Bw,
    void* __restrict__ O, int N) {
  constexpr int BM = 128, BK = 32;
  constexpr int AE = BM * BK / 8;
  constexpr int BE = BN * BK / 8;
  __shared__ short8 Asm[AE];
  __shared__ short8 Bsm[BE];
  __shared__ short8 Lsm[SPLIT ? BE : 1];
  const int tid = threadIdx.x;
  const int lane = tid & 63;
  const int wave = tid >> 6;
  const int m0 = blockIdx.x * BM;
  const int n0 = blockIdx.y * BN;
  const int wm = (BN == 128) ? (wave >> 1) * 64 : wave * 32;
  const int wn = (BN == 128) ? (wave & 1) * 64 : 0;
  constexpr int MT = (BN == 128) ? 4 : 2;
  constexpr int NT = 4;
  f32x4 acc[MT][NT] = {};
  const int e0 = tid, e1 = tid + 256;
  const int r0 = ((e0 >> 6) << 4) | (e0 & 15), q0 = (e0 >> 4) & 3;
  const int r1 = ((e1 >> 6) << 4) | (e1 & 15), q1 = (e1 >> 4) & 3;
  const unsigned short* Au = (const unsigned short*)A;
  const unsigned short* Bu = (const unsigned short*)Bw;
  const unsigned short* Lu = Bu + (SPLIT ? WSZ_ : 0);
  for (int k0 = 0; k0 < C_; k0 += BK) {
    __syncthreads();   // all ds_reads of previous iteration complete
    gl2lds(&Au[(size_t)(m0 + r0) * C_ + k0 + q0 * 8], &Asm[e0]);
    gl2lds(&Au[(size_t)(m0 + r1) * C_ + k0 + q1 * 8], &Asm[e1]);
    gl2lds(&Bu[(size_t)(n0 + r0) * C_ + k0 + q0 * 8], &Bsm[e0]);
    if constexpr (BN == 128)
      gl2lds(&Bu[(size_t)(n0 + r1) * C_ + k0 + q1 * 8], &Bsm[e1]);
    if constexpr (SPLIT) {
      gl2lds(&Lu[(size_t)(n0 + r0) * C_ + k0 + q0 * 8], &Lsm[e0]);
      if constexpr (BN == 128)
        gl2lds(&Lu[(size_t)(n0 + r1) * C_ + k0 + q1 * 8], &Lsm[e1]);
    }
    __syncthreads();   // implicit vmcnt(0) drain -> LDS tile ready
    short8 af[MT], bh[NT];
    #pragma unroll
    for (int mt = 0; mt < MT; ++mt) af[mt] = Asm[((wm >> 4) + mt) * 64 + lane];
    #pragma unroll
    for (int nt = 0; nt < NT; ++nt) bh[nt] = Bsm[((wn >> 4) + nt) * 64 + lane];
    #pragma unroll
    for (int mt = 0; mt < MT; ++mt)
      #pragma unroll
      for (int nt = 0; nt < NT; ++nt)
        acc[mt][nt] = __builtin_amdgcn_mfma_f32_16x16x32_bf16(
            af[mt], bh[nt], acc[mt][nt], 0, 0, 0);
    if constexpr (SPLIT) {
      short8 bl[NT];
      #pragma unroll
      for (int nt = 0; nt < NT; ++nt) bl[nt] = Lsm[((wn >> 4) + nt) * 64 + lane];
      #pragma unroll
      for (int mt = 0; mt < MT; ++mt)
        #pragma unroll
        for (int nt = 0; nt < NT; ++nt)
          acc[mt][nt] = __builtin_amdgcn_mfma_f32_16x16x32_bf16(
              af[mt], bl[nt], acc[mt][nt], 0, 0, 0);
    }
  }
  const int col = lane & 15, qr = lane >> 4;
  #pragma unroll
  for (int mt = 0; mt < MT; ++mt) {
    int mrow = m0 + wm + mt * 16 + qr * 4;
    #pragma unroll
    for (int nt = 0; nt < NT; ++nt) {
      int nc = n0 + wn + nt * 16 + col;
      #pragma unroll
      for (int r = 0; r < 4; ++r) {
        float v = acc[mt][nt][r];
        if (MODE == 1) v = v / (1.f + __expf(-v));
        if (MODE == 3) v = tanhf(v);
        size_t oi = (size_t)(mrow + r) * N + nc;
        if (MODE == 2) ((float*)O)[oi] = v;
        else           ((bf16*)O)[oi] = f2b(v);
      }
    }
  }
}

// ---------------------------------------------------------------------------
// mix_mfma (verified round 0): five K=32 GEMMs via MFMA fused with the
// elementwise epilogue x_f = x + (xshift-x)*(tm_f + m_f).
// ---------------------------------------------------------------------------
__global__ __launch_bounds__(256) void mix_mfma_kernel(
    const bf16* __restrict__ mix5, const bf16* __restrict__ w2p,
    const float* __restrict__ x,
    const float* __restrict__ tmw, const float* __restrict__ tmk,
    const float* __restrict__ tmv, const float* __restrict__ tmr,
    const float* __restrict__ tmg,
    bf16* __restrict__ xw, bf16* __restrict__ xk, bf16* __restrict__ xv,
    bf16* __restrict__ xr, bf16* __restrict__ xg) {
  constexpr int LDP = 200;
  __shared__ __align__(16) unsigned short Asm[64 * LDP];
  __shared__ __align__(16) unsigned short Bsm[64 * LDP];
  const int tid = threadIdx.x;
  const int row0 = blockIdx.x * 64;
  const int col0 = blockIdx.y * 64;
  const unsigned short* Au = (const unsigned short*)mix5;
  const unsigned short* Bu = (const unsigned short*)w2p;
  #pragma unroll
  for (int e0 = 0; e0 < 64 * 20; e0 += 256) {
    int e = e0 + tid;
    int rr = e / 20, p = e - rr * 20;
    *(short8*)&Asm[rr * LDP + p * 8] =
        *(const short8*)&Au[(size_t)(row0 + rr) * 192 + p * 8];
    *(short8*)&Bsm[rr * LDP + p * 8] =
        *(const short8*)&Bu[(size_t)(col0 + rr) * 192 + p * 8];
  }
  __syncthreads();
  const int lane = tid & 63, wave = tid >> 6;
  const int fl = lane & 15, q = lane >> 4;
  short8 af[5];
  #pragma unroll
  for (int f = 0; f < 5; ++f)
    af[f] = *(const short8*)&Asm[(wave * 16 + fl) * LDP + f * 32 + q * 8];
  f32x4 acc[4][5] = {};
  #pragma unroll
  for (int nt = 0; nt < 4; ++nt)
    #pragma unroll
    for (int f = 0; f < 5; ++f) {
      short8 bfr = *(const short8*)&Bsm[(nt * 16 + fl) * LDP + f * 32 + q * 8];
      acc[nt][f] = __builtin_amdgcn_mfma_f32_16x16x32_bf16(
          af[f], bfr, acc[nt][f], 0, 0, 0);
    }
  #pragma unroll
  for (int nt = 0; nt < 4; ++nt) {
    int cc = col0 + nt * 16 + fl;
    float vw = tmw[cc], vk = tmk[cc], vv = tmv[cc], vr = tmr[cc],
          vg = tmg[cc];
    #pragma unroll
    for (int r = 0; r < 4; ++r) {
      int rr = row0 + wave * 16 + q * 4 + r;
      size_t idx = (size_t)rr * C_ + cc;
      float xc = x[idx];
      float xx = (((rr & (T_ - 1)) == 0) ? 0.f : x[idx - C_]) - xc;
      xw[idx] = f2b(xc + xx * (vw + acc[nt][0][r]));
      xk[idx] = f2b(xc + xx * (vk + acc[nt][1][r]));
      xv[idx] = f2b(xc + xx * (vv + acc[nt][2][r]));
      xr[idx] = f2b(xc + xx * (vr + acc[nt][3][r]));
      xg[idx] = f2b(xc + xx * (vg + acc[nt][4][r]));
    }
  }
}

// ---------------------------------------------------------------------------
// decay (unchanged, verified): w = td + h1 @ Wd2 (K=64); ee = exp(w) bf16.
// ---------------------------------------------------------------------------
__global__ __launch_bounds__(512) void decay_kernel(
    const bf16* __restrict__ h1, const float* __restrict__ wd2,
    const float* __restrict__ tdecay, bf16* __restrict__ ee) {
  __shared__ float Hs[8][64];
  int row0 = blockIdx.x * 8;
  {
    int e = threadIdx.x;
    Hs[e >> 6][e & 63] = b2f(h1[(size_t)(row0 + (e >> 6)) * 64 + (e & 63)]);
  }
  __syncthreads();
  int c = threadIdx.x;
  float acc[8] = {0.f,0.f,0.f,0.f,0.f,0.f,0.f,0.f};
  for (int j = 0; j < 64; ++j) {
    float wv = wd2[j * C_ + c];
    #pragma unroll
    for (int r = 0; r < 8; ++r) acc[r] += Hs[r][j] * wv;
  }
  float td = tdecay[c];
  #pragma unroll
  for (int r = 0; r < 8; ++r)
    ee[(size_t)(row0 + r) * C_ + c] = f2b(expf(td + acc[r]));
}

// ---------------------------------------------------------------------------
// WKV6 chunked scan — 4-wave form, vectorized loads (round 3).
// Lane mapping for staging: t-row = wave*16 + it2*8 + (lane>>3),
// c4 = (lane&7)*4 -> each thread loads short4 (8B) of k/v/r per row.
// ---------------------------------------------------------------------------
__global__ __launch_bounds__(256) void wkv_partial_mfma(
    const bf16* __restrict__ k, const bf16* __restrict__ v,
    const bf16* __restrict__ ee, float* __restrict__ st) {
  __shared__ __align__(16) char smem[17536];
  float* Lm  = (float*)smem;              // [65][32] floats, 8320 B
  bf16*  K2T = (bf16*)(smem + 8320);      // [32][72]
  bf16*  VT  = (bf16*)(smem + 12928);     // [32][72]
  bf16*  Eb  = K2T;                       // [64][32] scratch (dead pre-stage)
  int g = blockIdx.x;
  int bh = g >> 5, c = g & (NC_ - 1);
  int b = bh >> 4, h = bh & 15;
  const int tid = threadIdx.x;
  const int lane = tid & 63, wave = tid >> 6;
  const int tl = lane >> 3;              // 0..7
  const int c4 = (lane & 7) * 4;
  size_t gbase = (size_t)b * T_ * C_ + (size_t)(c * CL_) * C_ + h * HS_;
  const short* ku = (const short*)k;
  const short* vu = (const short*)v;
  const short* eu = (const short*)ee;
  #pragma unroll
  for (int it = 0; it < 2; ++it) {       // ee tile, 8B per thread per iter
    int e4 = it * 256 + tid;             // 0..511
    int row = e4 >> 3, cc = (e4 & 7) * 4;
    short4v ev = *(const short4v*)&eu[gbase + (size_t)row * C_ + cc];
    *(short4v*)&((short*)Eb)[row * 32 + cc] = ev;
  }
  short4v k4[2], v4[2];
  #pragma unroll
  for (int it2 = 0; it2 < 2; ++it2) {
    int t = wave * 16 + it2 * 8 + tl;
    k4[it2] = *(const short4v*)&ku[gbase + (size_t)t * C_ + c4];
    v4[it2] = *(const short4v*)&vu[gbase + (size_t)t * C_ + c4];
  }
  __syncthreads();
  if (tid < 32) {
    float L = 0.f;
    for (int t = 0; t < CL_; ++t) {
      Lm[t * 32 + tid] = L;
      L -= b2f(Eb[t * 32 + tid]);
    }
    Lm[64 * 32 + tid] = L;
  }
  __syncthreads();
  f32x4 Ltot4 = *(const f32x4*)&Lm[64 * 32 + c4];
  #pragma unroll
  for (int it2 = 0; it2 < 2; ++it2) {
    int t = wave * 16 + it2 * 8 + tl;
    f32x4 Lt14 = *(const f32x4*)&Lm[(t + 1) * 32 + c4];
    #pragma unroll
    for (int j = 0; j < 4; ++j) {
      ((short*)K2T)[(c4 + j) * 72 + t] =
          f2s(s2f(k4[it2][j]) * __expf(Ltot4[j] - Lt14[j]));
      ((short*)VT)[(c4 + j) * 72 + t] = v4[it2][j];
    }
  }
  __syncthreads();
  const int fl = lane & 15, q = lane >> 4;
  const int mt = wave >> 1, nt = wave & 1;
  f32x4 accS = {};
  #pragma unroll
  for (int kc = 0; kc < 2; ++kc) {
    short8 av = *(const short8*)(VT + (mt * 16 + fl) * 72 + kc * 32 + q * 8);
    short8 bk = *(const short8*)(K2T + (nt * 16 + fl) * 72 + kc * 32 + q * 8);
    accS = __builtin_amdgcn_mfma_f32_16x16x32_bf16(av, bk, accS, 0, 0, 0);
  }
  size_t sbase = (size_t)g * STF_;
  #pragma unroll
  for (int r = 0; r < 4; ++r)
    st[sbase + (size_t)(mt * 16 + q * 4 + r) * 32 + nt * 16 + fl] = accS[r];
  if (tid < 32) st[sbase + 1024 + tid] = __expf(Lm[64 * 32 + tid]);
}

// ---------------------------------------------------------------------------
// stitch: serial chunk recurrence R = P*R + Sc per (bh), depth-1 software
// pipeline: chunk c+1's loads issue before chunk c's store+FMA chain.
// Incoming state for chunk c emitted bf16 hi/lo into dead S-region of slot
// c-1 (single wave -> program order makes the overwrite safe).
// ---------------------------------------------------------------------------
__global__ __launch_bounds__(64) void wkv_stitch_kernel(float* __restrict__ st) {
  int bh = blockIdx.x;
  int lane = threadIdx.x;
  int i = lane & 31, half = lane >> 5;
  float R[16];
  #pragma unroll
  for (int jj = 0; jj < 16; ++jj) R[jj] = 0.f;
  size_t s0 = (size_t)bh * NC_ * STF_;
  const int off = i * 32 + (half << 4);
  const int poff = 1024 + (half << 4);
  f32x4 Sc[4], Pj[4];
  {
    const f32x4* sp = (const f32x4*)(st + s0 + off);
    const f32x4* pp = (const f32x4*)(st + s0 + poff);
    #pragma unroll
    for (int q = 0; q < 4; ++q) { Sc[q] = sp[q]; Pj[q] = pp[q]; }
  }
  for (int c = 0; c < NC_; ++c) {
    size_t s = s0 + (size_t)c * STF_;
    f32x4 Sn[4], Pn[4];
    if (c + 1 < NC_) {
      const f32x4* sp = (const f32x4*)(st + s + STF_ + off);
      const f32x4* pp = (const f32x4*)(st + s + STF_ + poff);
      #pragma unroll
      for (int q = 0; q < 4; ++q) { Sn[q] = sp[q]; Pn[q] = pp[q]; }
    }
    if (c > 0) {
      __align__(16) short hi16[16], lo16[16];
      #pragma unroll
      for (int jj = 0; jj < 16; ++jj) {
        short hb = f2s(R[jj]);
        hi16[jj] = hb;
        lo16[jj] = f2s(R[jj] - s2f(hb));
      }
      short* sb = (short*)(st + s - STF_);
      *(short8*)&sb[off]         = *(const short8*)&hi16[0];
      *(short8*)&sb[off + 8]     = *(const short8*)&hi16[8];
      *(short8*)&sb[1024 + off]     = *(const short8*)&lo16[0];
      *(short8*)&sb[1024 + off + 8] = *(const short8*)&lo16[8];
    }
    #pragma unroll
    for (int q = 0; q < 4; ++q)
      #pragma unroll
      for (int j = 0; j < 4; ++j)
        R[q * 4 + j] = fmaf(Pj[q][j], R[q * 4 + j], Sc[q][j]);
    if (c + 1 < NC_) {
      #pragma unroll
      for (int q = 0; q < 4; ++q) { Sc[q] = Sn[q]; Pj[q] = Pn[q]; }
    }
  }
}

// ---------------------------------------------------------------------------
// wkv_final: 4-wave + fused groupnorm + vectorized staging (round 3).
// S fragments direct from stitched bf16 hi/lo state (slot g-1).
// ---------------------------------------------------------------------------
__global__ __launch_bounds__(256) void wkv_final_mfma(
    const bf16* __restrict__ r, const bf16* __restrict__ k,
    const bf16* __restrict__ v, const bf16* __restrict__ ee,
    const float* __restrict__ faaaa, const float* __restrict__ st,
    const bf16* __restrict__ gg, const float* __restrict__ lnw,
    const float* __restrict__ lnb, bf16* __restrict__ z) {
  __shared__ __align__(16) char smem[24320];
  float* Lm = (float*)smem;               // [65][32] — aliased by Pm later
  bf16*  Pm = (bf16*)smem;                // [64][72]
  bf16*  RA = (bf16*)(smem + 9216);       // [64][40]
  bf16*  Kd = (bf16*)(smem + 14336);      // [64][40]
  bf16*  VT = (bf16*)(smem + 19456);      // [32][72]
  bf16*  Eb = VT;                         // [64][32] scratch (dead pre-stage)
  float* bon = (float*)(smem + 24064);    // [64]
  int g = blockIdx.x;
  int bh = g >> 5, c = g & (NC_ - 1);
  int b = bh >> 4, h = bh & 15;
  const int tid = threadIdx.x;
  const int lane = tid & 63, wave = tid >> 6;
  const int tl = lane >> 3;              // 0..7
  const int c4 = (lane & 7) * 4;
  const int fl = lane & 15, q = lane >> 4;
  size_t gbase = (size_t)b * T_ * C_ + (size_t)(c * CL_) * C_ + h * HS_;
  size_t sbase = (size_t)g * STF_;
  const short* ru = (const short*)r;
  const short* ku = (const short*)k;
  const short* vu = (const short*)v;
  const short* eu = (const short*)ee;
  // ee tile -> LDS scratch (8B loads); S fragments from global; r/k/v regs
  #pragma unroll
  for (int it = 0; it < 2; ++it) {
    int e4 = it * 256 + tid;
    int row = e4 >> 3, cc = (e4 & 7) * 4;
    short4v ev = *(const short4v*)&eu[gbase + (size_t)row * C_ + cc];
    *(short4v*)&((short*)Eb)[row * 32 + cc] = ev;
  }
  short8 sh[2] = {}, sl[2] = {};
  if (c != 0) {
    const unsigned short* sb = (const unsigned short*)(st + sbase - STF_);
    #pragma unroll
    for (int nt = 0; nt < 2; ++nt) {
      sh[nt] = *(const short8*)&sb[(nt * 16 + fl) * 32 + q * 8];
      sl[nt] = *(const short8*)&sb[1024 + (nt * 16 + fl) * 32 + q * 8];
    }
  }
  short4v r4[2], k4[2], v4[2];
  #pragma unroll
  for (int it2 = 0; it2 < 2; ++it2) {
    int t = wave * 16 + it2 * 8 + tl;
    size_t gi = gbase + (size_t)t * C_ + c4;
    r4[it2] = *(const short4v*)&ru[gi];
    k4[it2] = *(const short4v*)&ku[gi];
    v4[it2] = *(const short4v*)&vu[gi];
  }
  __syncthreads();
  // serial prefix scan on LDS latency only
  if (tid < 32) {
    float L = 0.f;
    for (int t = 0; t < CL_; ++t) {
      Lm[t * 32 + tid] = L;
      L -= b2f(Eb[t * 32 + tid]);
    }
    Lm[64 * 32 + tid] = L;
  }
  __syncthreads();
  f32x4 u4 = *(const f32x4*)&faaaa[h * HS_ + c4];
  #pragma unroll
  for (int it2 = 0; it2 < 2; ++it2) {
    int t = wave * 16 + it2 * 8 + tl;
    f32x4 Lt4  = *(const f32x4*)&Lm[t * 32 + c4];
    f32x4 Lt14 = *(const f32x4*)&Lm[(t + 1) * 32 + c4];
    short4v ra4, kd4;
    float pb = 0.f;
    #pragma unroll
    for (int j = 0; j < 4; ++j) {
      float rvj = s2f(r4[it2][j]);
      float kvj = s2f(k4[it2][j]);
      ra4[j] = f2s(rvj * __expf(Lt4[j]));
      kd4[j] = f2s(kvj * __expf(-Lt14[j]));
      ((short*)VT)[(c4 + j) * 72 + t] = v4[it2][j];
      pb += rvj * u4[j] * kvj;
    }
    *(short4v*)&((short*)RA)[t * 40 + c4] = ra4;
    *(short4v*)&((short*)Kd)[t * 40 + c4] = kd4;
    pb += __shfl_xor(pb, 1); pb += __shfl_xor(pb, 2); pb += __shfl_xor(pb, 4);
    if ((lane & 7) == 0) bon[t] = pb;
  }
  __syncthreads();
  short8 afr = *(const short8*)(RA + (wave * 16 + fl) * 40 + q * 8);
  f32x4 accY[2] = {};
  #pragma unroll
  for (int nt = 0; nt < 2; ++nt) {
    accY[nt] = __builtin_amdgcn_mfma_f32_16x16x32_bf16(afr, sh[nt], accY[nt], 0, 0, 0);
    accY[nt] = __builtin_amdgcn_mfma_f32_16x16x32_bf16(afr, sl[nt], accY[nt], 0, 0, 0);
  }
  f32x4 accP[4] = {};
  #pragma unroll
  for (int s4 = 0; s4 < 4; ++s4) {
    short8 bk = *(const short8*)(Kd + (s4 * 16 + fl) * 40 + q * 8);
    accP[s4] = __builtin_amdgcn_mfma_f32_16x16x32_bf16(afr, bk, accP[s4], 0, 0, 0);
  }
  // write own Pm band (Lm dead: last read was pre-MFMA barrier)
  #pragma unroll
  for (int s4 = 0; s4 < 4; ++s4)
    #pragma unroll
    for (int rr = 0; rr < 4; ++rr) {
      int t = wave * 16 + q * 4 + rr;
      int s = s4 * 16 + fl;
      float pv = accP[s4][rr];
      float bv = bon[t];
      pv = (s < t) ? pv : ((s == t) ? bv : 0.f);
      Pm[t * 72 + s] = f2b(pv);
    }
  __syncthreads();
  #pragma unroll
  for (int kc = 0; kc < 2; ++kc) {
    short8 ap = *(const short8*)(Pm + (wave * 16 + fl) * 72 + kc * 32 + q * 8);
    #pragma unroll
    for (int nt = 0; nt < 2; ++nt) {
      short8 bv = *(const short8*)(VT + (nt * 16 + fl) * 72 + kc * 32 + q * 8);
      accY[nt] = __builtin_amdgcn_mfma_f32_16x16x32_bf16(ap, bv, accY[nt], 0, 0, 0);
    }
  }
  // fused groupnorm epilogue
  float lw0 = lnw[h * HS_ + fl],      lb0 = lnb[h * HS_ + fl];
  float lw1 = lnw[h * HS_ + 16 + fl], lb1 = lnb[h * HS_ + 16 + fl];
  #pragma unroll
  for (int rr = 0; rr < 4; ++rr) {
    int t = wave * 16 + q * 4 + rr;
    float a0 = accY[0][rr], a1 = accY[1][rr];
    float mu = a0 + a1;
    mu += __shfl_xor(mu, 1); mu += __shfl_xor(mu, 2);
    mu += __shfl_xor(mu, 4); mu += __shfl_xor(mu, 8);
    mu *= (1.f / 32.f);
    float d0 = a0 - mu, d1 = a1 - mu;
    float ss = d0 * d0 + d1 * d1;
    ss += __shfl_xor(ss, 1); ss += __shfl_xor(ss, 2);
    ss += __shfl_xor(ss, 4); ss += __shfl_xor(ss, 8);
    float rs = rsqrtf(ss * (1.f / 32.f) + 1e-5f);
    size_t gi = gbase + (size_t)t * C_;
    float g0 = b2f(gg[gi + fl]);
    float g1 = b2f(gg[gi + 16 + fl]);
    z[gi + fl]      = f2b((d0 * rs * lw0 + lb0) * g0);
    z[gi + 16 + fl] = f2b((d1 * rs * lw1 + lb1) * g1);
  }
}

// ---------------------------------------------------------------------------
extern "C" void kernel_launch(void* const* d_in, const int* in_sizes, int n_in,
                              void* d_out, int out_size, void* d_ws, size_t ws_size,
                              hipStream_t stream) {
  (void)in_sizes; (void)n_in; (void)out_size; (void)ws_size;
  const float* x      = (const float*)d_in[0];
  const float* tmx    = (const float*)d_in[1];
  const float* tmw    = (const float*)d_in[2];
  const float* tmk    = (const float*)d_in[3];
  const float* tmv    = (const float*)d_in[4];
  const float* tmr    = (const float*)d_in[5];
  const float* tmg    = (const float*)d_in[6];
  const float* w1     = (const float*)d_in[7];
  const float* w2     = (const float*)d_in[8];
  const float* tdecay = (const float*)d_in[9];
  const float* wd1    = (const float*)d_in[10];
  const float* wd2    = (const float*)d_in[11];
  const float* faaaa  = (const float*)d_in[12];
  const float* Wr     = (const float*)d_in[13];
  const float* Wk     = (const float*)d_in[14];
  const float* Wv     = (const float*)d_in[15];
  const float* Wg     = (const float*)d_in[16];
  const float* Wo     = (const float*)d_in[17];
  const float* lnw    = (const float*)d_in[18];
  const float* lnb    = (const float*)d_in[19];
  float* out = (float*)d_out;

  // workspace layout — 6 x 16MB slots + st + weights; peak ~118 MB
  char* w8 = (char*)d_ws;
  const size_t MB = 1024ull * 1024ull;
  bf16* S0 = (bf16*)(w8 +  0 * MB);  // xxx -> xw -> ee
  bf16* S1 = (bf16*)(w8 + 16 * MB);  // xk -> vb
  bf16* S2 = (bf16*)(w8 + 32 * MB);  // xv -> gb
  bf16* S3 = (bf16*)(w8 + 48 * MB);  // xr -> kb
  bf16* S4 = (bf16*)(w8 + 64 * MB);  // xg -> z
  bf16* S5 = (bf16*)(w8 + 80 * MB);  // mix5p+h1 -> rb
  float* st = (float*)(w8 + 96 * MB);            // 16.5 MB
  char* wreg = w8 + 112 * MB + 512 * 1024;       // weights at 112.5 MB
  bf16* Wrb  = (bf16*)(wreg);
  bf16* Wkb  = Wrb + 2 * WSZ_;
  bf16* Wvb  = Wkb + 2 * WSZ_;
  bf16* Wgb  = Wvb + 2 * WSZ_;
  bf16* Wob  = Wgb + 2 * WSZ_;
  bf16* w1p  = Wob + 2 * WSZ_;                   // [192][512]
  bf16* wd1p = w1p + 192 * 512;                  // [64][512]
  bf16* w2p  = wd1p + 64 * 512;                  // [512][192]
  bf16* mix5p = S5;                              // [16384][192], 6 MB
  bf16* h1    = S5 + (size_t)BT_ * 192;          // [16384][64],  2 MB

  // 1. fused prep: xxx (S0) + weight splits + w1/wd1/w2 transpose
  prep_combo_kernel<<<PREP_N_, 256, 0, stream>>>(
      x, tmx, Wr, Wk, Wv, Wg, Wo, w1, wd1, w2,
      S0, Wrb, Wkb, Wvb, Wgb, Wob, w1p, wd1p, w2p);
  // 2. mix5p = tanh(xxx @ w1p^T)
  mfma_gemm_kernel<64, 3, 0><<<dim3(128, 3), 256, 0, stream>>>(S0, w1p, mix5p, 192);
  // 3. all five mixed activations in one MFMA pass (xxx dead -> xw over S0)
  mix_mfma_kernel<<<dim3(BT_ / 64, 8), 256, 0, stream>>>(
      mix5p, w2p, x, tmw, tmk, tmv, tmr, tmg, S0, S1, S2, S3, S4);
  // 4. h1 = tanh(xw @ wd1^T);  5. ee = exp(td + h1 @ wd2)  (ee over xw slot)
  mfma_gemm_kernel<64, 3, 0><<<dim3(128, 1), 256, 0, stream>>>(S0, wd1p, h1, 64);
  decay_kernel<<<BT_ / 8, 512, 0, stream>>>(h1, wd2, tdecay, S0);
  // 6-9. projections (split weights)
  dim3 gg(128, 4);
  mfma_gemm_kernel<128, 0, 1><<<gg, 256, 0, stream>>>(S3, Wrb, S5, C_);  // xr->rb(S5)
  mfma_gemm_kernel<128, 0, 1><<<gg, 256, 0, stream>>>(S1, Wkb, S3, C_);  // xk->kb(S3)
  mfma_gemm_kernel<128, 0, 1><<<gg, 256, 0, stream>>>(S2, Wvb, S1, C_);  // xv->vb(S1)
  mfma_gemm_kernel<128, 1, 1><<<gg, 256, 0, stream>>>(S4, Wgb, S2, C_);  // xg->gb(S2), silu
  // 10-12. chunk-parallel WKV6 scan (4-wave MFMA form, gnorm fused in final)
  wkv_partial_mfma<<<B_ * H_ * NC_, 256, 0, stream>>>(S3, S1, S0, st);
  wkv_stitch_kernel<<<B_ * H_, 64, 0, stream>>>(st);
  wkv_final_mfma<<<B_ * H_ * NC_, 256, 0, stream>>>(S5, S3, S1, S0, faaaa, st,
                                                    S2, lnw, lnb, S4);
  // 13. output projection (fp32) reads fused-gnorm z (S4)
  mfma_gemm_kernel<128, 2, 1><<<gg, 256, 0, stream>>>(S4, Wob, out, C_);
}